// Round 1
// 666.703 us; speedup vs baseline: 1.0467x; 1.0467x over previous
//
#include <hip/hip_runtime.h>
#include <cstdint>

// ResMLP + top2-MoE + final LN on MI355X.
// R5: T2 LDS XOR-swizzle on all four MFMA GEMMs. Fragment reads were
// ds_read_b128 at stride-128B (row*128 + chunk*16) -> 8/16-way bank
// conflicts (SQ_LDS_BANK_CONFLICT = 2.5e7/dispatch ~= 33% of CU-cycles on
// gemm1). Fix per rule-21: linear global_load_lds dest, pre-swizzled
// global SOURCE chunk (c2 ^= row&7; same 128B segment, coalescing kept),
// and the same XOR on every ds_read address (byte ^= (row&7)<<4).

#define NTOK 4096
#define HD 1024
#define MLPH 4096
#define EXPH 2048
#define NEXP 8
#define KSPLIT 4
#define KCH 1024
#define MAXSLOT 9216

typedef __attribute__((ext_vector_type(8))) _Float16 f16x8;
typedef __attribute__((ext_vector_type(4))) float f32x4v;

__device__ __forceinline__ float gelu_f(float v) {
  return 0.5f * v * (1.0f + erff(v * 0.7071067811865475f));
}

__device__ __forceinline__ void load16_lds(const void* g, void* lds) {
  __builtin_amdgcn_global_load_lds(
      (__attribute__((address_space(1))) unsigned int*)(uintptr_t)g,
      (__attribute__((address_space(3))) unsigned int*)(unsigned)(uintptr_t)lds,
      16, 0, 0);
}

// ---------------- merged transpose+convert (w1 & w2) ----------------
__global__ void transpose_split2(const float* __restrict__ w1, const float* __restrict__ w2,
                                 _Float16* __restrict__ o1h, _Float16* __restrict__ o1l,
                                 _Float16* __restrict__ o2h, _Float16* __restrict__ o2l) {
  __shared__ float t[32][33];
  int z = blockIdx.z;
  const float* in = z ? w2 : w1;
  _Float16* oh = z ? o2h : o1h;
  _Float16* ol = z ? o2l : o1l;
  int R = z ? MLPH : HD, C = z ? HD : MLPH;
  int c0 = (z ? blockIdx.y : blockIdx.x) * 32;
  int r0 = (z ? blockIdx.x : blockIdx.y) * 32;
  int tx = threadIdx.x & 31, ty = threadIdx.x >> 5;
#pragma unroll
  for (int i = 0; i < 4; ++i)
    t[ty + i * 8][tx] = in[(size_t)(r0 + ty + i * 8) * C + c0 + tx];
  __syncthreads();
#pragma unroll
  for (int i = 0; i < 4; ++i) {
    float v = t[tx][ty + i * 8];
    _Float16 h = (_Float16)v;
    size_t o = (size_t)(c0 + ty + i * 8) * R + r0 + tx;
    oh[o] = h;
    ol[o] = (_Float16)((v - (float)h) * 2048.0f);
  }
}

// ---------------- merged expert-weight transpose ----------------
__global__ void transpose_f16_2(const float* __restrict__ ew1, const float* __restrict__ ew2,
                                _Float16* __restrict__ ew1t, _Float16* __restrict__ ew2t) {
  __shared__ float t[32][33];
  int z = blockIdx.z;
  const float* in;
  _Float16* out;
  int R, C, c0, r0;
  if (z < 8) {
    in = ew1 + (size_t)z * HD * EXPH; out = ew1t + (size_t)z * HD * EXPH;
    R = HD; C = EXPH; c0 = blockIdx.x * 32; r0 = blockIdx.y * 32;
  } else {
    int e = z - 8;
    in = ew2 + (size_t)e * EXPH * HD; out = ew2t + (size_t)e * EXPH * HD;
    R = EXPH; C = HD; c0 = blockIdx.y * 32; r0 = blockIdx.x * 32;
  }
  int tx = threadIdx.x & 31, ty = threadIdx.x >> 5;
#pragma unroll
  for (int i = 0; i < 4; ++i)
    t[ty + i * 8][tx] = in[(size_t)(r0 + ty + i * 8) * C + c0 + tx];
  __syncthreads();
#pragma unroll
  for (int i = 0; i < 4; ++i)
    out[(size_t)(c0 + ty + i * 8) * R + r0 + tx] = (_Float16)t[tx][ty + i * 8];
}

// ---------------- LN1 ----------------
__global__ void ln1_kernel(const float* __restrict__ x, const float* __restrict__ g,
                           const float* __restrict__ b,
                           _Float16* __restrict__ oh, _Float16* __restrict__ ol) {
  int row = blockIdx.x, tid = threadIdx.x;
  const float4* xr = (const float4*)(x + (size_t)row * HD);
  float4 v = xr[tid];
  float s = v.x + v.y + v.z + v.w;
  float s2 = v.x * v.x + v.y * v.y + v.z * v.z + v.w * v.w;
  __shared__ float red[8];
#pragma unroll
  for (int o = 32; o > 0; o >>= 1) { s += __shfl_xor(s, o, 64); s2 += __shfl_xor(s2, o, 64); }
  if ((tid & 63) == 0) { red[tid >> 6] = s; red[(tid >> 6) + 4] = s2; }
  __syncthreads();
  s = red[0] + red[1] + red[2] + red[3];
  s2 = red[4] + red[5] + red[6] + red[7];
  float mu = s * (1.0f / HD);
  float rstd = 1.0f / sqrtf(s2 * (1.0f / HD) - mu * mu + 1e-5f);
  float4 gv = ((const float4*)g)[tid], bv = ((const float4*)b)[tid];
  float y[4];
  y[0] = (v.x - mu) * rstd * gv.x + bv.x;
  y[1] = (v.y - mu) * rstd * gv.y + bv.y;
  y[2] = (v.z - mu) * rstd * gv.z + bv.z;
  y[3] = (v.w - mu) * rstd * gv.w + bv.w;
  size_t base = (size_t)row * HD + tid * 4;
#pragma unroll
  for (int j = 0; j < 4; ++j) {
    _Float16 h = (_Float16)y[j];
    oh[base + j] = h;
    ol[base + j] = (_Float16)((y[j] - (float)h) * 2048.0f);
  }
}

// ---------------- split-fp16 GEMM, gelu epilogue (resmlp gemm1), BK=64 -------
// T2: LDS chunk index XOR-swizzled with row&7 (source-side + read-side).
__global__ __launch_bounds__(256, 2) void gemm_split_gelu(
    const _Float16* __restrict__ Ah, const _Float16* __restrict__ Al,
    const _Float16* __restrict__ Bh, const _Float16* __restrict__ Bl,
    const float* __restrict__ bias,
    _Float16* __restrict__ outh, _Float16* __restrict__ outl, int N, int K) {
  int m0 = blockIdx.y * 128, n0 = blockIdx.x * 128;
  __shared__ __align__(16) _Float16 sAh[128 * 64], sAl[128 * 64];
  __shared__ __align__(16) _Float16 sBh[128 * 64], sBl[128 * 64];
  int tid = threadIdx.x, wave = tid >> 6, lane = tid & 63;
  int wm = wave >> 1, wn = wave & 1;
  f32x4v acc1[4][4] = {};
  f32x4v acc2[4][4] = {};
  const _Float16* pAh = Ah + (size_t)m0 * K;
  const _Float16* pAl = Al + (size_t)m0 * K;
  const _Float16* pBh = Bh + (size_t)n0 * K;
  const _Float16* pBl = Bl + (size_t)n0 * K;
  int r16 = lane & 15, q = lane >> 4;
  for (int k0 = 0; k0 < K; k0 += 64) {
    __syncthreads();
#pragma unroll
    for (int i = 0; i < 4; ++i) {
      int s = i * 256 + wave * 64 + lane;
      int row = s >> 3, c2 = s & 7;
      int c2s = c2 ^ (row & 7);  // pre-swizzled source; LDS dest stays linear
      size_t goff = (size_t)row * K + k0 + c2s * 8;
      int loff = (i * 256 + wave * 64) * 16;
      load16_lds(pAh + goff, (char*)sAh + loff);
      load16_lds(pAl + goff, (char*)sAl + loff);
      load16_lds(pBh + goff, (char*)sBh + loff);
      load16_lds(pBl + goff, (char*)sBl + loff);
    }
    __syncthreads();
#pragma unroll
    for (int ks = 0; ks < 2; ++ks) {
      f16x8 bh[4], bl[4];
#pragma unroll
      for (int t = 0; t < 4; ++t) {
        int rowb = wn * 64 + t * 16 + r16;
        int rb = rowb * 64 + ((ks * 4 + q) ^ (rowb & 7)) * 8;
        bh[t] = *(const f16x8*)&sBh[rb];
        bl[t] = *(const f16x8*)&sBl[rb];
      }
#pragma unroll
      for (int mt = 0; mt < 4; ++mt) {
        int rowa = wm * 64 + mt * 16 + r16;
        int ra = rowa * 64 + ((ks * 4 + q) ^ (rowa & 7)) * 8;
        f16x8 ah = *(const f16x8*)&sAh[ra];
        f16x8 al = *(const f16x8*)&sAl[ra];
#pragma unroll
        for (int nt = 0; nt < 4; ++nt) {
          acc1[mt][nt] = __builtin_amdgcn_mfma_f32_16x16x32_f16(ah, bh[nt], acc1[mt][nt], 0, 0, 0);
          acc2[mt][nt] = __builtin_amdgcn_mfma_f32_16x16x32_f16(al, bh[nt], acc2[mt][nt], 0, 0, 0);
        }
#pragma unroll
        for (int nt = 0; nt < 4; ++nt)
          acc2[mt][nt] = __builtin_amdgcn_mfma_f32_16x16x32_f16(ah, bl[nt], acc2[mt][nt], 0, 0, 0);
      }
    }
  }
#pragma unroll
  for (int mt = 0; mt < 4; ++mt)
#pragma unroll
    for (int nt = 0; nt < 4; ++nt) {
      int col = n0 + wn * 64 + nt * 16 + r16;
      float bv = bias[col];
#pragma unroll
      for (int r = 0; r < 4; ++r) {
        size_t grow = (size_t)(m0 + wm * 64 + mt * 16 + q * 4 + r);
        float v = acc1[mt][nt][r] + acc2[mt][nt][r] * (1.0f / 2048.0f) + bv;
        v = gelu_f(v);
        _Float16 h = (_Float16)v;
        outh[grow * N + col] = h;
        outl[grow * N + col] = (_Float16)((v - (float)h) * 2048.0f);
      }
    }
}

// ------ split-fp16 GEMM, split-K partials (resmlp gemm2), BK=64, swizzled ----
__global__ __launch_bounds__(256, 2) void gemm_split_pk(
    const _Float16* __restrict__ Ah, const _Float16* __restrict__ Al,
    const _Float16* __restrict__ Bh, const _Float16* __restrict__ Bl,
    float* __restrict__ part, int N, int K) {
  int L = blockIdx.x + 8 * (blockIdx.y + 32 * blockIdx.z);
  int g8 = L & 7, j = L >> 3;
  int yz = g8 * 16 + (j >> 3);
  int bx = j & 7;
  int by = yz & 31;
  int bz = yz >> 5;
  int m0 = by * 128, n0 = bx * 128;
  int kbase = bz * KCH;
  __shared__ __align__(16) _Float16 sAh[128 * 64], sAl[128 * 64];
  __shared__ __align__(16) _Float16 sBh[128 * 64], sBl[128 * 64];
  int tid = threadIdx.x, wave = tid >> 6, lane = tid & 63;
  int wm = wave >> 1, wn = wave & 1;
  f32x4v acc1[4][4] = {};
  f32x4v acc2[4][4] = {};
  const _Float16* pAh = Ah + (size_t)m0 * K + kbase;
  const _Float16* pAl = Al + (size_t)m0 * K + kbase;
  const _Float16* pBh = Bh + (size_t)n0 * K + kbase;
  const _Float16* pBl = Bl + (size_t)n0 * K + kbase;
  int r16 = lane & 15, q = lane >> 4;
  for (int k0 = 0; k0 < KCH; k0 += 64) {
    __syncthreads();
#pragma unroll
    for (int i = 0; i < 4; ++i) {
      int s = i * 256 + wave * 64 + lane;
      int row = s >> 3, c2 = s & 7;
      int c2s = c2 ^ (row & 7);
      size_t goff = (size_t)row * K + k0 + c2s * 8;
      int loff = (i * 256 + wave * 64) * 16;
      load16_lds(pAh + goff, (char*)sAh + loff);
      load16_lds(pAl + goff, (char*)sAl + loff);
      load16_lds(pBh + goff, (char*)sBh + loff);
      load16_lds(pBl + goff, (char*)sBl + loff);
    }
    __syncthreads();
#pragma unroll
    for (int ks = 0; ks < 2; ++ks) {
      f16x8 bh[4], bl[4];
#pragma unroll
      for (int t = 0; t < 4; ++t) {
        int rowb = wn * 64 + t * 16 + r16;
        int rb = rowb * 64 + ((ks * 4 + q) ^ (rowb & 7)) * 8;
        bh[t] = *(const f16x8*)&sBh[rb];
        bl[t] = *(const f16x8*)&sBl[rb];
      }
#pragma unroll
      for (int mt = 0; mt < 4; ++mt) {
        int rowa = wm * 64 + mt * 16 + r16;
        int ra = rowa * 64 + ((ks * 4 + q) ^ (rowa & 7)) * 8;
        f16x8 ah = *(const f16x8*)&sAh[ra];
        f16x8 al = *(const f16x8*)&sAl[ra];
#pragma unroll
        for (int nt = 0; nt < 4; ++nt) {
          acc1[mt][nt] = __builtin_amdgcn_mfma_f32_16x16x32_f16(ah, bh[nt], acc1[mt][nt], 0, 0, 0);
          acc2[mt][nt] = __builtin_amdgcn_mfma_f32_16x16x32_f16(al, bh[nt], acc2[mt][nt], 0, 0, 0);
        }
#pragma unroll
        for (int nt = 0; nt < 4; ++nt)
          acc2[mt][nt] = __builtin_amdgcn_mfma_f32_16x16x32_f16(ah, bl[nt], acc2[mt][nt], 0, 0, 0);
      }
    }
  }
  float* pz = part + (size_t)bz * NTOK * HD;
#pragma unroll
  for (int mt = 0; mt < 4; ++mt)
#pragma unroll
    for (int nt = 0; nt < 4; ++nt) {
      int col = n0 + wn * 64 + nt * 16 + r16;
#pragma unroll
      for (int r = 0; r < 4; ++r) {
        size_t grow = (size_t)(m0 + wm * 64 + mt * 16 + q * 4 + r);
        pz[grow * N + col] = acc1[mt][nt][r] + acc2[mt][nt][r] * (1.0f / 2048.0f);
      }
    }
}

// ------- reduce partials + bias + residual + LN2 + router (fused) -------
__global__ void reduce_ln2_router_kernel(
    const float* __restrict__ part, const float* __restrict__ x,
    const float* __restrict__ b2, const float* __restrict__ g,
    const float* __restrict__ b, const float* __restrict__ rw,
    _Float16* __restrict__ x2h, int* __restrict__ tidx, float* __restrict__ twt,
    int* __restrict__ counts) {
  int row = blockIdx.x, tid = threadIdx.x;
  int lane = tid & 63, wid = tid >> 6;
  float4 v = {0, 0, 0, 0};
#pragma unroll
  for (int z = 0; z < KSPLIT; ++z) {
    float4 p = ((const float4*)(part + ((size_t)z * NTOK + row) * HD))[tid];
    v.x += p.x; v.y += p.y; v.z += p.z; v.w += p.w;
  }
  float4 bb = ((const float4*)b2)[tid];
  float4 xv = ((const float4*)(x + (size_t)row * HD))[tid];
  v.x += bb.x + xv.x; v.y += bb.y + xv.y; v.z += bb.z + xv.z; v.w += bb.w + xv.w;
  float s = v.x + v.y + v.z + v.w;
  float s2 = v.x * v.x + v.y * v.y + v.z * v.z + v.w * v.w;
  __shared__ float red[8];
  __shared__ float sred[4][8];
#pragma unroll
  for (int o = 32; o > 0; o >>= 1) { s += __shfl_xor(s, o, 64); s2 += __shfl_xor(s2, o, 64); }
  if (lane == 0) { red[wid] = s; red[wid + 4] = s2; }
  __syncthreads();
  s = red[0] + red[1] + red[2] + red[3];
  s2 = red[4] + red[5] + red[6] + red[7];
  float mu = s * (1.0f / HD);
  float rstd = 1.0f / sqrtf(s2 * (1.0f / HD) - mu * mu + 1e-5f);
  float4 gv = ((const float4*)g)[tid], bv = ((const float4*)b)[tid];
  float4 o4;
  o4.x = (v.x - mu) * rstd * gv.x + bv.x + v.x;
  o4.y = (v.y - mu) * rstd * gv.y + bv.y + v.y;
  o4.z = (v.z - mu) * rstd * gv.z + bv.z + v.z;
  o4.w = (v.w - mu) * rstd * gv.w + bv.w + v.w;
  size_t base = (size_t)row * HD + tid * 4;
  x2h[base + 0] = (_Float16)o4.x;
  x2h[base + 1] = (_Float16)o4.y;
  x2h[base + 2] = (_Float16)o4.z;
  x2h[base + 3] = (_Float16)o4.w;
  float lg[8] = {0, 0, 0, 0, 0, 0, 0, 0};
  {
    const float4* rp = (const float4*)(rw + (size_t)tid * 32);
    float xc[4] = {o4.x, o4.y, o4.z, o4.w};
#pragma unroll
    for (int jj = 0; jj < 4; ++jj) {
      float4 r0 = rp[jj * 2], r1 = rp[jj * 2 + 1];
      lg[0] += xc[jj] * r0.x; lg[1] += xc[jj] * r0.y;
      lg[2] += xc[jj] * r0.z; lg[3] += xc[jj] * r0.w;
      lg[4] += xc[jj] * r1.x; lg[5] += xc[jj] * r1.y;
      lg[6] += xc[jj] * r1.z; lg[7] += xc[jj] * r1.w;
    }
  }
#pragma unroll
  for (int o = 32; o > 0; o >>= 1)
#pragma unroll
    for (int e = 0; e < 8; ++e) lg[e] += __shfl_xor(lg[e], o, 64);
  if (lane == 0)
#pragma unroll
    for (int e = 0; e < 8; ++e) sred[wid][e] = lg[e];
  __syncthreads();
  if (tid == 0) {
    float l8[8];
#pragma unroll
    for (int e = 0; e < 8; ++e)
      l8[e] = sred[0][e] + sred[1][e] + sred[2][e] + sred[3][e];
    int e0 = 0; float m0v = l8[0];
#pragma unroll
    for (int e = 1; e < 8; ++e) if (l8[e] > m0v) { m0v = l8[e]; e0 = e; }
    int e1 = -1; float m1v = -3.4e38f;
#pragma unroll
    for (int e = 0; e < 8; ++e) if (e != e0 && l8[e] > m1v) { m1v = l8[e]; e1 = e; }
    float p0 = 1.0f / (1.0f + expf(m1v - m0v));
    tidx[2 * row] = e0; tidx[2 * row + 1] = e1;
    twt[2 * row] = p0; twt[2 * row + 1] = 1.0f - p0;
    atomicAdd(&counts[e0], 1);
    atomicAdd(&counts[e1], 1);
  }
}

// ------- offsets + aux + scatter + slot->token (single block) -------
__global__ void route_block(const int* __restrict__ counts, const int* __restrict__ tidx,
                            int* __restrict__ poff_g, float* __restrict__ auxp,
                            int* __restrict__ slotmap, int* __restrict__ slot2token) {
  __shared__ int poff[9];
  __shared__ int cur[8];
  int tid = threadIdx.x;
  if (tid == 0) {
    int acc = 0; poff[0] = 0; float aux = 0.0f;
    for (int e = 0; e < NEXP; ++e) {
      int c = counts[e];
      float load = (float)c / (float)(NTOK * 2);
      aux += load * logf(load + 1e-9f);
      acc += ((c + 127) >> 7) << 7;
      poff[e + 1] = acc;
    }
    auxp[0] = 0.01f * aux;
  }
  if (tid < 8) cur[tid] = 0;
  __syncthreads();
  for (int t = tid; t < NTOK; t += 256) {
#pragma unroll
    for (int k = 0; k < 2; ++k) {
      int e = tidx[2 * t + k];
      int slot = poff[e] + atomicAdd(&cur[e], 1);
      slotmap[2 * t + k] = slot;
      slot2token[slot] = t;
    }
  }
  __syncthreads();
  // pad slots -> token 0 (compute discarded in combine)
  for (int e = 0; e < NEXP; ++e) {
    int lo = poff[e] + counts[e], hi = poff[e + 1];
    for (int s2 = lo + tid; s2 < hi; s2 += 256) slot2token[s2] = 0;
  }
  if (tid < 9) poff_g[tid] = poff[tid];
}

// ------- single-fp16 GEMM (experts, padded buckets), BK=64, swizzled -------
// EPI==0: A rows indirect via slot2token (x2h source), gelu -> fp16
// EPI==1: A rows direct (a1), +bias -> fp32
template <int EPI>
__global__ __launch_bounds__(256, 2) void gemm_expert(
    const _Float16* __restrict__ A, const _Float16* __restrict__ B,
    const float* __restrict__ bias, void* __restrict__ out,
    int N, int K, const int* __restrict__ poff, size_t bstride, int bias_stride,
    const int* __restrict__ s2t) {
  int e = blockIdx.z;
  int lo = poff[e], hi = poff[e + 1];
  int m0 = lo + blockIdx.y * 128;
  if (m0 >= hi) return;
  const _Float16* Bt = B + (size_t)e * bstride;
  const float* bias_e = bias + (size_t)e * bias_stride;
  int n0 = blockIdx.x * 128;
  __shared__ __align__(16) _Float16 sA[128 * 64];
  __shared__ __align__(16) _Float16 sB[128 * 64];
  int tid = threadIdx.x, wave = tid >> 6, lane = tid & 63;
  int wm = wave >> 1, wn = wave & 1;
  int r16 = lane & 15, q = lane >> 4;
  f32x4v acc[4][4] = {};
  // row sources are k-invariant: hoist (incl. slot->token indirection);
  // swizzle key is the LDS row (= tile row), applied to source chunk c2.
  size_t aoff[4]; size_t boff[4];
#pragma unroll
  for (int i = 0; i < 4; ++i) {
    int s = i * 256 + wave * 64 + lane;
    int row = s >> 3, c2 = s & 7;
    int c2s = c2 ^ (row & 7);
    int am = m0 + row;
    size_t arow = (EPI == 0) ? (size_t)s2t[am] : (size_t)am;
    aoff[i] = arow * K + c2s * 8;
    boff[i] = (size_t)(n0 + row) * K + c2s * 8;
  }
  for (int k0 = 0; k0 < K; k0 += 64) {
    __syncthreads();
#pragma unroll
    for (int i = 0; i < 4; ++i) {
      int loff = (i * 256 + wave * 64) * 16;
      load16_lds(A + aoff[i] + k0, (char*)sA + loff);
      load16_lds(Bt + boff[i] + k0, (char*)sB + loff);
    }
    __syncthreads();
#pragma unroll
    for (int ks = 0; ks < 2; ++ks) {
      f16x8 bf[4];
#pragma unroll
      for (int t = 0; t < 4; ++t) {
        int rowb = wn * 64 + t * 16 + r16;
        bf[t] = *(const f16x8*)&sB[rowb * 64 + ((ks * 4 + q) ^ (rowb & 7)) * 8];
      }
#pragma unroll
      for (int mt = 0; mt < 4; ++mt) {
        int rowa = wm * 64 + mt * 16 + r16;
        f16x8 af = *(const f16x8*)&sA[rowa * 64 + ((ks * 4 + q) ^ (rowa & 7)) * 8];
#pragma unroll
        for (int nt = 0; nt < 4; ++nt)
          acc[mt][nt] = __builtin_amdgcn_mfma_f32_16x16x32_f16(af, bf[nt], acc[mt][nt], 0, 0, 0);
      }
    }
  }
#pragma unroll
  for (int mt = 0; mt < 4; ++mt)
#pragma unroll
    for (int nt = 0; nt < 4; ++nt) {
      int col = n0 + wn * 64 + nt * 16 + r16;
      float bv = bias_e[col];
#pragma unroll
      for (int r = 0; r < 4; ++r) {
        size_t grow = (size_t)(m0 + wm * 64 + mt * 16 + q * 4 + r);
        float v = acc[mt][nt][r] + bv;
        if (EPI == 0)
          ((_Float16*)out)[grow * N + col] = (_Float16)gelu_f(v);
        else
          ((float*)out)[grow * N + col] = v;
      }
    }
}

// ---------------- combine + final LN ----------------
__global__ void combine_ln_kernel(const float* __restrict__ ybuf, const int* __restrict__ slotmap,
                                  const float* __restrict__ twt, const float* __restrict__ g,
                                  const float* __restrict__ b, float* __restrict__ out) {
  int t = blockIdx.x, tid = threadIdx.x;
  int s0 = slotmap[2 * t], s1 = slotmap[2 * t + 1];
  float w0 = twt[2 * t], w1 = twt[2 * t + 1];
  float4 a = ((const float4*)(ybuf + (size_t)s0 * HD))[tid];
  float4 c = ((const float4*)(ybuf + (size_t)s1 * HD))[tid];
  float4 v;
  v.x = w0 * a.x + w1 * c.x; v.y = w0 * a.y + w1 * c.y;
  v.z = w0 * a.z + w1 * c.z; v.w = w0 * a.w + w1 * c.w;
  float s = v.x + v.y + v.z + v.w;
  float s2 = v.x * v.x + v.y * v.y + v.z * v.z + v.w * v.w;
  __shared__ float red[8];
#pragma unroll
  for (int o = 32; o > 0; o >>= 1) { s += __shfl_xor(s, o, 64); s2 += __shfl_xor(s2, o, 64); }
  if ((tid & 63) == 0) { red[tid >> 6] = s; red[(tid >> 6) + 4] = s2; }
  __syncthreads();
  s = red[0] + red[1] + red[2] + red[3];
  s2 = red[4] + red[5] + red[6] + red[7];
  float mu = s * (1.0f / HD);
  float rstd = 1.0f / sqrtf(s2 * (1.0f / HD) - mu * mu + 1e-5f);
  float4 gv = ((const float4*)g)[tid], bv = ((const float4*)b)[tid];
  float4 o4;
  o4.x = (v.x - mu) * rstd * gv.x + bv.x;
  o4.y = (v.y - mu) * rstd * gv.y + bv.y;
  o4.z = (v.z - mu) * rstd * gv.z + bv.z;
  o4.w = (v.w - mu) * rstd * gv.w + bv.w;
  ((float4*)(out + (size_t)t * HD))[tid] = o4;
}

// ---------------- launch ----------------
extern "C" void kernel_launch(void* const* d_in, const int* in_sizes, int n_in,
                              void* d_out, int out_size, void* d_ws, size_t ws_size,
                              hipStream_t stream) {
  const float* x    = (const float*)d_in[0];
  const float* ln1g = (const float*)d_in[1];
  const float* ln1b = (const float*)d_in[2];
  const float* ln2g = (const float*)d_in[3];
  const float* ln2b = (const float*)d_in[4];
  const float* w1   = (const float*)d_in[5];
  const float* b1   = (const float*)d_in[6];
  const float* w2   = (const float*)d_in[7];
  const float* b2   = (const float*)d_in[8];
  const float* rw   = (const float*)d_in[9];
  const float* ew1  = (const float*)d_in[10];
  const float* eb1  = (const float*)d_in[11];
  const float* ew2  = (const float*)d_in[12];
  const float* eb2  = (const float*)d_in[13];
  const float* lnfg = (const float*)d_in[14];
  const float* lnfb = (const float*)d_in[15];

  char* ws = (char*)d_ws;
  _Float16* acth = (_Float16*)(ws + 0);
  _Float16* actl = (_Float16*)(ws + 33554432);
  _Float16* ew2t = (_Float16*)(ws + 0);
  _Float16* ew1t = (_Float16*)(ws + 33554432);
  _Float16* w1th = (_Float16*)(ws + 67108864);
  _Float16* w1tl = (_Float16*)(ws + 75497472);
  _Float16* x2h  = (_Float16*)(ws + 67108864);
  _Float16* w2th = (_Float16*)(ws + 83886080);
  _Float16* w2tl = (_Float16*)(ws + 92274688);
  _Float16* h1h  = (_Float16*)(ws + 100663296);
  _Float16* h1l  = (_Float16*)(ws + 109051904);
  float*    part = (float*)(ws + 100663296);   // 4 x [4096,1024] f32 = 64 MB
  float*    ybuf = (float*)(ws + 100663296);   // [MAXSLOT,1024] f32 (after reduce)
  _Float16* a1   = (_Float16*)(ws + 167772160);
  const size_t offS = 205520896;
  int*   counts     = (int*)(ws + offS);
  int*   poff       = (int*)(ws + offS + 64);
  int*   tidx       = (int*)(ws + offS + 1024);
  float* twt        = (float*)(ws + offS + 1024 + 32768);
  int*   slotmap    = (int*)(ws + offS + 1024 + 65536);
  int*   slot2token = (int*)(ws + offS + 1024 + 98304);

  float* out  = (float*)d_out;
  float* auxp = out + (size_t)NTOK * HD;

  dim3 b256(256);
  hipMemsetAsync(ws + offS, 0, 64, stream);

  // resmlp weight conversion (expert transposes deferred: dst overlays act)
  transpose_split2<<<dim3(128, 32, 2), b256, 0, stream>>>(w1, w2, w1th, w1tl, w2th, w2tl);

  // resmlp
  ln1_kernel<<<NTOK, b256, 0, stream>>>(x, ln1g, ln1b, h1h, h1l);
  gemm_split_gelu<<<dim3(MLPH / 128, NTOK / 128, 1), b256, 0, stream>>>(
      h1h, h1l, w1th, w1tl, b1, acth, actl, MLPH, HD);
  gemm_split_pk<<<dim3(HD / 128, NTOK / 128, KSPLIT), b256, 0, stream>>>(
      acth, actl, w2th, w2tl, part, HD, MLPH);
  reduce_ln2_router_kernel<<<NTOK, b256, 0, stream>>>(
      part, x, b2, ln2g, ln2b, rw, x2h, tidx, twt, counts);

  // expert weight transposes (act region now dead)
  transpose_f16_2<<<dim3(64, 32, 16), b256, 0, stream>>>(ew1, ew2, ew1t, ew2t);

  // routing tail (single block): offsets + aux + scatter + slot->token
  route_block<<<1, b256, 0, stream>>>(counts, tidx, poff, auxp, slotmap, slot2token);

  // experts (padded buckets, early-exit grid); eg1 gathers A from x2h via s2t
  gemm_expert<0><<<dim3(EXPH / 128, NTOK / 128, NEXP), b256, 0, stream>>>(
      x2h, ew1t, eb1, a1, EXPH, HD, poff, (size_t)EXPH * HD, EXPH, slot2token);
  gemm_expert<1><<<dim3(HD / 128, NTOK / 128, NEXP), b256, 0, stream>>>(
      a1, ew2t, eb2, ybuf, HD, EXPH, poff, (size_t)HD * EXPH, HD, nullptr);

  // combine + final LN
  combine_ln_kernel<<<NTOK, b256, 0, stream>>>(ybuf, slotmap, twt, lnfg, lnfb, out);
}

// Round 2
// 554.465 us; speedup vs baseline: 1.2586x; 1.2024x over previous
//
#include <hip/hip_runtime.h>
#include <cstdint>

// ResMLP + top2-MoE + final LN on MI355X.
// R6: (a) resmlp GEMMs dropped from split-fp16 (3 MFMA passes) to plain
// single-pass fp16 — the MoE path already runs plain fp16 on both operands
// and passes; plain-fp16 resmlp adds ~4e-4 dot error vs the ~0.016 fp16
// residual-stream quantization already tolerated (absmax pinned at 2^-5
// across rounds). Removes h1l/actl/w1tl/w2tl buffers + traffic entirely.
// (b) KSPLIT 4->2 (still 2 blocks/CU; halves partial write+read traffic),
// bijective XCD-chunked block swizzle for pk. T2 LDS XOR-swizzle kept on
// all GEMMs (R5: bank conflicts 2.5e7 -> 0).

#define NTOK 4096
#define HD 1024
#define MLPH 4096
#define EXPH 2048
#define NEXP 8
#define KSPLIT 2
#define KCH 2048
#define MAXSLOT 9216

typedef __attribute__((ext_vector_type(8))) _Float16 f16x8;
typedef __attribute__((ext_vector_type(4))) float f32x4v;

__device__ __forceinline__ float gelu_f(float v) {
  return 0.5f * v * (1.0f + erff(v * 0.7071067811865475f));
}

__device__ __forceinline__ void load16_lds(const void* g, void* lds) {
  __builtin_amdgcn_global_load_lds(
      (__attribute__((address_space(1))) unsigned int*)(uintptr_t)g,
      (__attribute__((address_space(3))) unsigned int*)(unsigned)(uintptr_t)lds,
      16, 0, 0);
}

// ---------------- merged transpose+convert (w1 & w2, fp16 only) -------------
__global__ void transpose_conv2(const float* __restrict__ w1, const float* __restrict__ w2,
                                _Float16* __restrict__ o1, _Float16* __restrict__ o2) {
  __shared__ float t[32][33];
  int z = blockIdx.z;
  const float* in = z ? w2 : w1;
  _Float16* oh = z ? o2 : o1;
  int R = z ? MLPH : HD, C = z ? HD : MLPH;
  int c0 = (z ? blockIdx.y : blockIdx.x) * 32;
  int r0 = (z ? blockIdx.x : blockIdx.y) * 32;
  int tx = threadIdx.x & 31, ty = threadIdx.x >> 5;
#pragma unroll
  for (int i = 0; i < 4; ++i)
    t[ty + i * 8][tx] = in[(size_t)(r0 + ty + i * 8) * C + c0 + tx];
  __syncthreads();
#pragma unroll
  for (int i = 0; i < 4; ++i)
    oh[(size_t)(c0 + ty + i * 8) * R + r0 + tx] = (_Float16)t[tx][ty + i * 8];
}

// ---------------- merged expert-weight transpose ----------------
__global__ void transpose_f16_2(const float* __restrict__ ew1, const float* __restrict__ ew2,
                                _Float16* __restrict__ ew1t, _Float16* __restrict__ ew2t) {
  __shared__ float t[32][33];
  int z = blockIdx.z;
  const float* in;
  _Float16* out;
  int R, C, c0, r0;
  if (z < 8) {
    in = ew1 + (size_t)z * HD * EXPH; out = ew1t + (size_t)z * HD * EXPH;
    R = HD; C = EXPH; c0 = blockIdx.x * 32; r0 = blockIdx.y * 32;
  } else {
    int e = z - 8;
    in = ew2 + (size_t)e * EXPH * HD; out = ew2t + (size_t)e * EXPH * HD;
    R = EXPH; C = HD; c0 = blockIdx.y * 32; r0 = blockIdx.x * 32;
  }
  int tx = threadIdx.x & 31, ty = threadIdx.x >> 5;
#pragma unroll
  for (int i = 0; i < 4; ++i)
    t[ty + i * 8][tx] = in[(size_t)(r0 + ty + i * 8) * C + c0 + tx];
  __syncthreads();
#pragma unroll
  for (int i = 0; i < 4; ++i)
    out[(size_t)(c0 + ty + i * 8) * R + r0 + tx] = (_Float16)t[tx][ty + i * 8];
}

// ---------------- LN1 (fp16 out) ----------------
__global__ void ln1_kernel(const float* __restrict__ x, const float* __restrict__ g,
                           const float* __restrict__ b, _Float16* __restrict__ oh) {
  int row = blockIdx.x, tid = threadIdx.x;
  const float4* xr = (const float4*)(x + (size_t)row * HD);
  float4 v = xr[tid];
  float s = v.x + v.y + v.z + v.w;
  float s2 = v.x * v.x + v.y * v.y + v.z * v.z + v.w * v.w;
  __shared__ float red[8];
#pragma unroll
  for (int o = 32; o > 0; o >>= 1) { s += __shfl_xor(s, o, 64); s2 += __shfl_xor(s2, o, 64); }
  if ((tid & 63) == 0) { red[tid >> 6] = s; red[(tid >> 6) + 4] = s2; }
  __syncthreads();
  s = red[0] + red[1] + red[2] + red[3];
  s2 = red[4] + red[5] + red[6] + red[7];
  float mu = s * (1.0f / HD);
  float rstd = 1.0f / sqrtf(s2 * (1.0f / HD) - mu * mu + 1e-5f);
  float4 gv = ((const float4*)g)[tid], bv = ((const float4*)b)[tid];
  size_t base = (size_t)row * HD + tid * 4;
  oh[base + 0] = (_Float16)((v.x - mu) * rstd * gv.x + bv.x);
  oh[base + 1] = (_Float16)((v.y - mu) * rstd * gv.y + bv.y);
  oh[base + 2] = (_Float16)((v.z - mu) * rstd * gv.z + bv.z);
  oh[base + 3] = (_Float16)((v.w - mu) * rstd * gv.w + bv.w);
}

// ------- plain fp16 GEMM, gelu epilogue (resmlp gemm1), BK=64, T2 swz -------
__global__ __launch_bounds__(256, 2) void gemm_f16_gelu(
    const _Float16* __restrict__ A, const _Float16* __restrict__ B,
    const float* __restrict__ bias, _Float16* __restrict__ out, int N, int K) {
  int m0 = blockIdx.y * 128, n0 = blockIdx.x * 128;
  __shared__ __align__(16) _Float16 sA[128 * 64], sB[128 * 64];
  int tid = threadIdx.x, wave = tid >> 6, lane = tid & 63;
  int wm = wave >> 1, wn = wave & 1;
  int r16 = lane & 15, q = lane >> 4;
  f32x4v acc[4][4] = {};
  const _Float16* pA = A + (size_t)m0 * K;
  const _Float16* pB = B + (size_t)n0 * K;
  for (int k0 = 0; k0 < K; k0 += 64) {
    __syncthreads();
#pragma unroll
    for (int i = 0; i < 4; ++i) {
      int s = i * 256 + wave * 64 + lane;
      int row = s >> 3, c2 = s & 7;
      int c2s = c2 ^ (row & 7);
      size_t goff = (size_t)row * K + k0 + c2s * 8;
      int loff = (i * 256 + wave * 64) * 16;
      load16_lds(pA + goff, (char*)sA + loff);
      load16_lds(pB + goff, (char*)sB + loff);
    }
    __syncthreads();
#pragma unroll
    for (int ks = 0; ks < 2; ++ks) {
      f16x8 bf[4];
#pragma unroll
      for (int t = 0; t < 4; ++t) {
        int rowb = wn * 64 + t * 16 + r16;
        bf[t] = *(const f16x8*)&sB[rowb * 64 + ((ks * 4 + q) ^ (rowb & 7)) * 8];
      }
#pragma unroll
      for (int mt = 0; mt < 4; ++mt) {
        int rowa = wm * 64 + mt * 16 + r16;
        f16x8 af = *(const f16x8*)&sA[rowa * 64 + ((ks * 4 + q) ^ (rowa & 7)) * 8];
#pragma unroll
        for (int nt = 0; nt < 4; ++nt)
          acc[mt][nt] = __builtin_amdgcn_mfma_f32_16x16x32_f16(af, bf[nt], acc[mt][nt], 0, 0, 0);
      }
    }
  }
#pragma unroll
  for (int mt = 0; mt < 4; ++mt)
#pragma unroll
    for (int nt = 0; nt < 4; ++nt) {
      int col = n0 + wn * 64 + nt * 16 + r16;
      float bv = bias[col];
#pragma unroll
      for (int r = 0; r < 4; ++r) {
        size_t grow = (size_t)(m0 + wm * 64 + mt * 16 + q * 4 + r);
        out[grow * N + col] = (_Float16)gelu_f(acc[mt][nt][r] + bv);
      }
    }
}

// ------- plain fp16 GEMM, split-K partials (resmlp gemm2), BK=64, swz -------
__global__ __launch_bounds__(256, 2) void gemm_f16_pk(
    const _Float16* __restrict__ A, const _Float16* __restrict__ B,
    float* __restrict__ part, int N, int K) {
  // bijective XCD-chunked swizzle over 8*32*KSPLIT = 512 blocks (64/XCD)
  int orig = blockIdx.x + 8 * (blockIdx.y + 32 * blockIdx.z);
  int xcd = orig & 7, idx = orig >> 3;
  int wg = xcd * 64 + idx;
  int bz = wg >> 8;
  int rr = wg & 255;
  int by = rr >> 3, bx = rr & 7;
  int m0 = by * 128, n0 = bx * 128;
  int kbase = bz * KCH;
  __shared__ __align__(16) _Float16 sA[128 * 64], sB[128 * 64];
  int tid = threadIdx.x, wave = tid >> 6, lane = tid & 63;
  int wm = wave >> 1, wn = wave & 1;
  int r16 = lane & 15, q = lane >> 4;
  f32x4v acc[4][4] = {};
  const _Float16* pA = A + (size_t)m0 * K + kbase;
  const _Float16* pB = B + (size_t)n0 * K + kbase;
  for (int k0 = 0; k0 < KCH; k0 += 64) {
    __syncthreads();
#pragma unroll
    for (int i = 0; i < 4; ++i) {
      int s = i * 256 + wave * 64 + lane;
      int row = s >> 3, c2 = s & 7;
      int c2s = c2 ^ (row & 7);
      size_t goff = (size_t)row * K + k0 + c2s * 8;
      int loff = (i * 256 + wave * 64) * 16;
      load16_lds(pA + goff, (char*)sA + loff);
      load16_lds(pB + goff, (char*)sB + loff);
    }
    __syncthreads();
#pragma unroll
    for (int ks = 0; ks < 2; ++ks) {
      f16x8 bf[4];
#pragma unroll
      for (int t = 0; t < 4; ++t) {
        int rowb = wn * 64 + t * 16 + r16;
        bf[t] = *(const f16x8*)&sB[rowb * 64 + ((ks * 4 + q) ^ (rowb & 7)) * 8];
      }
#pragma unroll
      for (int mt = 0; mt < 4; ++mt) {
        int rowa = wm * 64 + mt * 16 + r16;
        f16x8 af = *(const f16x8*)&sA[rowa * 64 + ((ks * 4 + q) ^ (rowa & 7)) * 8];
#pragma unroll
        for (int nt = 0; nt < 4; ++nt)
          acc[mt][nt] = __builtin_amdgcn_mfma_f32_16x16x32_f16(af, bf[nt], acc[mt][nt], 0, 0, 0);
      }
    }
  }
  float* pz = part + (size_t)bz * NTOK * HD;
#pragma unroll
  for (int mt = 0; mt < 4; ++mt)
#pragma unroll
    for (int nt = 0; nt < 4; ++nt) {
      int col = n0 + wn * 64 + nt * 16 + r16;
#pragma unroll
      for (int r = 0; r < 4; ++r) {
        size_t grow = (size_t)(m0 + wm * 64 + mt * 16 + q * 4 + r);
        pz[grow * N + col] = acc[mt][nt][r];
      }
    }
}

// ------- reduce partials + bias + residual + LN2 + router (fused) -------
__global__ void reduce_ln2_router_kernel(
    const float* __restrict__ part, const float* __restrict__ x,
    const float* __restrict__ b2, const float* __restrict__ g,
    const float* __restrict__ b, const float* __restrict__ rw,
    _Float16* __restrict__ x2h, int* __restrict__ tidx, float* __restrict__ twt,
    int* __restrict__ counts) {
  int row = blockIdx.x, tid = threadIdx.x;
  int lane = tid & 63, wid = tid >> 6;
  float4 v = {0, 0, 0, 0};
#pragma unroll
  for (int z = 0; z < KSPLIT; ++z) {
    float4 p = ((const float4*)(part + ((size_t)z * NTOK + row) * HD))[tid];
    v.x += p.x; v.y += p.y; v.z += p.z; v.w += p.w;
  }
  float4 bb = ((const float4*)b2)[tid];
  float4 xv = ((const float4*)(x + (size_t)row * HD))[tid];
  v.x += bb.x + xv.x; v.y += bb.y + xv.y; v.z += bb.z + xv.z; v.w += bb.w + xv.w;
  float s = v.x + v.y + v.z + v.w;
  float s2 = v.x * v.x + v.y * v.y + v.z * v.z + v.w * v.w;
  __shared__ float red[8];
  __shared__ float sred[4][8];
#pragma unroll
  for (int o = 32; o > 0; o >>= 1) { s += __shfl_xor(s, o, 64); s2 += __shfl_xor(s2, o, 64); }
  if (lane == 0) { red[wid] = s; red[wid + 4] = s2; }
  __syncthreads();
  s = red[0] + red[1] + red[2] + red[3];
  s2 = red[4] + red[5] + red[6] + red[7];
  float mu = s * (1.0f / HD);
  float rstd = 1.0f / sqrtf(s2 * (1.0f / HD) - mu * mu + 1e-5f);
  float4 gv = ((const float4*)g)[tid], bv = ((const float4*)b)[tid];
  float4 o4;
  o4.x = (v.x - mu) * rstd * gv.x + bv.x + v.x;
  o4.y = (v.y - mu) * rstd * gv.y + bv.y + v.y;
  o4.z = (v.z - mu) * rstd * gv.z + bv.z + v.z;
  o4.w = (v.w - mu) * rstd * gv.w + bv.w + v.w;
  size_t base = (size_t)row * HD + tid * 4;
  x2h[base + 0] = (_Float16)o4.x;
  x2h[base + 1] = (_Float16)o4.y;
  x2h[base + 2] = (_Float16)o4.z;
  x2h[base + 3] = (_Float16)o4.w;
  float lg[8] = {0, 0, 0, 0, 0, 0, 0, 0};
  {
    const float4* rp = (const float4*)(rw + (size_t)tid * 32);
    float xc[4] = {o4.x, o4.y, o4.z, o4.w};
#pragma unroll
    for (int jj = 0; jj < 4; ++jj) {
      float4 r0 = rp[jj * 2], r1 = rp[jj * 2 + 1];
      lg[0] += xc[jj] * r0.x; lg[1] += xc[jj] * r0.y;
      lg[2] += xc[jj] * r0.z; lg[3] += xc[jj] * r0.w;
      lg[4] += xc[jj] * r1.x; lg[5] += xc[jj] * r1.y;
      lg[6] += xc[jj] * r1.z; lg[7] += xc[jj] * r1.w;
    }
  }
#pragma unroll
  for (int o = 32; o > 0; o >>= 1)
#pragma unroll
    for (int e = 0; e < 8; ++e) lg[e] += __shfl_xor(lg[e], o, 64);
  if (lane == 0)
#pragma unroll
    for (int e = 0; e < 8; ++e) sred[wid][e] = lg[e];
  __syncthreads();
  if (tid == 0) {
    float l8[8];
#pragma unroll
    for (int e = 0; e < 8; ++e)
      l8[e] = sred[0][e] + sred[1][e] + sred[2][e] + sred[3][e];
    int e0 = 0; float m0v = l8[0];
#pragma unroll
    for (int e = 1; e < 8; ++e) if (l8[e] > m0v) { m0v = l8[e]; e0 = e; }
    int e1 = -1; float m1v = -3.4e38f;
#pragma unroll
    for (int e = 0; e < 8; ++e) if (e != e0 && l8[e] > m1v) { m1v = l8[e]; e1 = e; }
    float p0 = 1.0f / (1.0f + expf(m1v - m0v));
    tidx[2 * row] = e0; tidx[2 * row + 1] = e1;
    twt[2 * row] = p0; twt[2 * row + 1] = 1.0f - p0;
    atomicAdd(&counts[e0], 1);
    atomicAdd(&counts[e1], 1);
  }
}

// ------- offsets + aux + scatter + slot->token (single block) -------
__global__ void route_block(const int* __restrict__ counts, const int* __restrict__ tidx,
                            int* __restrict__ poff_g, float* __restrict__ auxp,
                            int* __restrict__ slotmap, int* __restrict__ slot2token) {
  __shared__ int poff[9];
  __shared__ int cur[8];
  int tid = threadIdx.x;
  if (tid == 0) {
    int acc = 0; poff[0] = 0; float aux = 0.0f;
    for (int e = 0; e < NEXP; ++e) {
      int c = counts[e];
      float load = (float)c / (float)(NTOK * 2);
      aux += load * logf(load + 1e-9f);
      acc += ((c + 127) >> 7) << 7;
      poff[e + 1] = acc;
    }
    auxp[0] = 0.01f * aux;
  }
  if (tid < 8) cur[tid] = 0;
  __syncthreads();
  for (int t = tid; t < NTOK; t += 256) {
#pragma unroll
    for (int k = 0; k < 2; ++k) {
      int e = tidx[2 * t + k];
      int slot = poff[e] + atomicAdd(&cur[e], 1);
      slotmap[2 * t + k] = slot;
      slot2token[slot] = t;
    }
  }
  __syncthreads();
  // pad slots -> token 0 (compute discarded in combine)
  for (int e = 0; e < NEXP; ++e) {
    int lo = poff[e] + counts[e], hi = poff[e + 1];
    for (int s2 = lo + tid; s2 < hi; s2 += 256) slot2token[s2] = 0;
  }
  if (tid < 9) poff_g[tid] = poff[tid];
}

// ------- single-fp16 GEMM (experts, padded buckets), BK=64, swizzled -------
// EPI==0: A rows indirect via slot2token (x2h source), gelu -> fp16
// EPI==1: A rows direct (a1), +bias -> fp32
template <int EPI>
__global__ __launch_bounds__(256, 2) void gemm_expert(
    const _Float16* __restrict__ A, const _Float16* __restrict__ B,
    const float* __restrict__ bias, void* __restrict__ out,
    int N, int K, const int* __restrict__ poff, size_t bstride, int bias_stride,
    const int* __restrict__ s2t) {
  int e = blockIdx.z;
  int lo = poff[e], hi = poff[e + 1];
  int m0 = lo + blockIdx.y * 128;
  if (m0 >= hi) return;
  const _Float16* Bt = B + (size_t)e * bstride;
  const float* bias_e = bias + (size_t)e * bias_stride;
  int n0 = blockIdx.x * 128;
  __shared__ __align__(16) _Float16 sA[128 * 64];
  __shared__ __align__(16) _Float16 sB[128 * 64];
  int tid = threadIdx.x, wave = tid >> 6, lane = tid & 63;
  int wm = wave >> 1, wn = wave & 1;
  int r16 = lane & 15, q = lane >> 4;
  f32x4v acc[4][4] = {};
  // row sources are k-invariant: hoist (incl. slot->token indirection);
  // swizzle key is the LDS row (= tile row), applied to source chunk c2.
  size_t aoff[4]; size_t boff[4];
#pragma unroll
  for (int i = 0; i < 4; ++i) {
    int s = i * 256 + wave * 64 + lane;
    int row = s >> 3, c2 = s & 7;
    int c2s = c2 ^ (row & 7);
    int am = m0 + row;
    size_t arow = (EPI == 0) ? (size_t)s2t[am] : (size_t)am;
    aoff[i] = arow * K + c2s * 8;
    boff[i] = (size_t)(n0 + row) * K + c2s * 8;
  }
  for (int k0 = 0; k0 < K; k0 += 64) {
    __syncthreads();
#pragma unroll
    for (int i = 0; i < 4; ++i) {
      int loff = (i * 256 + wave * 64) * 16;
      load16_lds(A + aoff[i] + k0, (char*)sA + loff);
      load16_lds(Bt + boff[i] + k0, (char*)sB + loff);
    }
    __syncthreads();
#pragma unroll
    for (int ks = 0; ks < 2; ++ks) {
      f16x8 bf[4];
#pragma unroll
      for (int t = 0; t < 4; ++t) {
        int rowb = wn * 64 + t * 16 + r16;
        bf[t] = *(const f16x8*)&sB[rowb * 64 + ((ks * 4 + q) ^ (rowb & 7)) * 8];
      }
#pragma unroll
      for (int mt = 0; mt < 4; ++mt) {
        int rowa = wm * 64 + mt * 16 + r16;
        f16x8 af = *(const f16x8*)&sA[rowa * 64 + ((ks * 4 + q) ^ (rowa & 7)) * 8];
#pragma unroll
        for (int nt = 0; nt < 4; ++nt)
          acc[mt][nt] = __builtin_amdgcn_mfma_f32_16x16x32_f16(af, bf[nt], acc[mt][nt], 0, 0, 0);
      }
    }
  }
#pragma unroll
  for (int mt = 0; mt < 4; ++mt)
#pragma unroll
    for (int nt = 0; nt < 4; ++nt) {
      int col = n0 + wn * 64 + nt * 16 + r16;
      float bv = bias_e[col];
#pragma unroll
      for (int r = 0; r < 4; ++r) {
        size_t grow = (size_t)(m0 + wm * 64 + mt * 16 + q * 4 + r);
        float v = acc[mt][nt][r] + bv;
        if (EPI == 0)
          ((_Float16*)out)[grow * N + col] = (_Float16)gelu_f(v);
        else
          ((float*)out)[grow * N + col] = v;
      }
    }
}

// ---------------- combine + final LN ----------------
__global__ void combine_ln_kernel(const float* __restrict__ ybuf, const int* __restrict__ slotmap,
                                  const float* __restrict__ twt, const float* __restrict__ g,
                                  const float* __restrict__ b, float* __restrict__ out) {
  int t = blockIdx.x, tid = threadIdx.x;
  int s0 = slotmap[2 * t], s1 = slotmap[2 * t + 1];
  float w0 = twt[2 * t], w1 = twt[2 * t + 1];
  float4 a = ((const float4*)(ybuf + (size_t)s0 * HD))[tid];
  float4 c = ((const float4*)(ybuf + (size_t)s1 * HD))[tid];
  float4 v;
  v.x = w0 * a.x + w1 * c.x; v.y = w0 * a.y + w1 * c.y;
  v.z = w0 * a.z + w1 * c.z; v.w = w0 * a.w + w1 * c.w;
  float s = v.x + v.y + v.z + v.w;
  float s2 = v.x * v.x + v.y * v.y + v.z * v.z + v.w * v.w;
  __shared__ float red[8];
#pragma unroll
  for (int o = 32; o > 0; o >>= 1) { s += __shfl_xor(s, o, 64); s2 += __shfl_xor(s2, o, 64); }
  if ((tid & 63) == 0) { red[tid >> 6] = s; red[(tid >> 6) + 4] = s2; }
  __syncthreads();
  s = red[0] + red[1] + red[2] + red[3];
  s2 = red[4] + red[5] + red[6] + red[7];
  float mu = s * (1.0f / HD);
  float rstd = 1.0f / sqrtf(s2 * (1.0f / HD) - mu * mu + 1e-5f);
  float4 gv = ((const float4*)g)[tid], bv = ((const float4*)b)[tid];
  float4 o4;
  o4.x = (v.x - mu) * rstd * gv.x + bv.x;
  o4.y = (v.y - mu) * rstd * gv.y + bv.y;
  o4.z = (v.z - mu) * rstd * gv.z + bv.z;
  o4.w = (v.w - mu) * rstd * gv.w + bv.w;
  ((float4*)(out + (size_t)t * HD))[tid] = o4;
}

// ---------------- launch ----------------
extern "C" void kernel_launch(void* const* d_in, const int* in_sizes, int n_in,
                              void* d_out, int out_size, void* d_ws, size_t ws_size,
                              hipStream_t stream) {
  const float* x    = (const float*)d_in[0];
  const float* ln1g = (const float*)d_in[1];
  const float* ln1b = (const float*)d_in[2];
  const float* ln2g = (const float*)d_in[3];
  const float* ln2b = (const float*)d_in[4];
  const float* w1   = (const float*)d_in[5];
  const float* b1   = (const float*)d_in[6];
  const float* w2   = (const float*)d_in[7];
  const float* b2   = (const float*)d_in[8];
  const float* rw   = (const float*)d_in[9];
  const float* ew1  = (const float*)d_in[10];
  const float* eb1  = (const float*)d_in[11];
  const float* ew2  = (const float*)d_in[12];
  const float* eb2  = (const float*)d_in[13];
  const float* lnfg = (const float*)d_in[14];
  const float* lnfb = (const float*)d_in[15];

  char* ws = (char*)d_ws;
  _Float16* acth = (_Float16*)(ws + 0);            // 32 MB [4096,4096] f16
  _Float16* ew2t = (_Float16*)(ws + 0);            // 32 MB (after pk)
  _Float16* ew1t = (_Float16*)(ws + 33554432);     // 32 MB
  _Float16* w1th = (_Float16*)(ws + 67108864);     // 8 MB
  _Float16* x2h  = (_Float16*)(ws + 67108864);     // 8 MB (after gemm1)
  _Float16* w2th = (_Float16*)(ws + 75497472);     // 8 MB
  _Float16* h1h  = (_Float16*)(ws + 100663296);    // 8 MB
  float*    part = (float*)(ws + 100663296);       // KSPLIT x [4096,1024] f32 = 32 MB
  float*    ybuf = (float*)(ws + 100663296);       // [MAXSLOT,1024] f32 (after reduce)
  _Float16* a1   = (_Float16*)(ws + 167772160);    // [MAXSLOT,2048] f16
  const size_t offS = 205520896;
  int*   counts     = (int*)(ws + offS);
  int*   poff       = (int*)(ws + offS + 64);
  int*   tidx       = (int*)(ws + offS + 1024);
  float* twt        = (float*)(ws + offS + 1024 + 32768);
  int*   slotmap    = (int*)(ws + offS + 1024 + 65536);
  int*   slot2token = (int*)(ws + offS + 1024 + 98304);

  float* out  = (float*)d_out;
  float* auxp = out + (size_t)NTOK * HD;

  dim3 b256(256);
  hipMemsetAsync(ws + offS, 0, 64, stream);

  // resmlp weight conversion (fp16 transposes)
  transpose_conv2<<<dim3(128, 32, 2), b256, 0, stream>>>(w1, w2, w1th, w2th);

  // resmlp
  ln1_kernel<<<NTOK, b256, 0, stream>>>(x, ln1g, ln1b, h1h);
  gemm_f16_gelu<<<dim3(MLPH / 128, NTOK / 128, 1), b256, 0, stream>>>(
      h1h, w1th, b1, acth, MLPH, HD);
  gemm_f16_pk<<<dim3(HD / 128, NTOK / 128, KSPLIT), b256, 0, stream>>>(
      acth, w2th, part, HD, MLPH);
  reduce_ln2_router_kernel<<<NTOK, b256, 0, stream>>>(
      part, x, b2, ln2g, ln2b, rw, x2h, tidx, twt, counts);

  // expert weight transposes (act region now dead)
  transpose_f16_2<<<dim3(64, 32, 16), b256, 0, stream>>>(ew1, ew2, ew1t, ew2t);

  // routing tail (single block): offsets + aux + scatter + slot->token
  route_block<<<1, b256, 0, stream>>>(counts, tidx, poff, auxp, slotmap, slot2token);

  // experts (padded buckets, early-exit grid); eg1 gathers A from x2h via s2t
  gemm_expert<0><<<dim3(EXPH / 128, NTOK / 128, NEXP), b256, 0, stream>>>(
      x2h, ew1t, eb1, a1, EXPH, HD, poff, (size_t)EXPH * HD, EXPH, slot2token);
  gemm_expert<1><<<dim3(HD / 128, NTOK / 128, NEXP), b256, 0, stream>>>(
      a1, ew2t, eb2, ybuf, HD, EXPH, poff, (size_t)HD * EXPH, HD, nullptr);

  // combine + final LN
  combine_ln_kernel<<<NTOK, b256, 0, stream>>>(ybuf, slotmap, twt, lnfg, lnfb, out);
}

// Round 3
// 544.171 us; speedup vs baseline: 1.2824x; 1.0189x over previous
//
#include <hip/hip_runtime.h>
#include <cstdint>

// ResMLP + top2-MoE + final LN on MI355X.
// R7: reduce_ln2_router was 103.7 us at 330 GB/s / 4.5% VALU / 0 MFMA —
// serialized on 8192 device-scope atomicAdds to ONE cacheline (counts[8];
// ~12ns each ~= 100us, matches). Fix: no global atomics anywhere. The
// router kernel only writes tidx/twt/x2h; route_block re-derives the
// histogram from tidx (L2-resident) with ballot-aggregated LDS atomics
// (1 atomic/wave/expert), then poff+aux, then ballot-aggregated scatter
// (slot order within an expert is arbitrary). counts buffer + memset gone.

#define NTOK 4096
#define HD 1024
#define MLPH 4096
#define EXPH 2048
#define NEXP 8
#define KSPLIT 2
#define KCH 2048
#define MAXSLOT 9216

typedef __attribute__((ext_vector_type(8))) _Float16 f16x8;
typedef __attribute__((ext_vector_type(4))) float f32x4v;

__device__ __forceinline__ float gelu_f(float v) {
  return 0.5f * v * (1.0f + erff(v * 0.7071067811865475f));
}

__device__ __forceinline__ void load16_lds(const void* g, void* lds) {
  __builtin_amdgcn_global_load_lds(
      (__attribute__((address_space(1))) unsigned int*)(uintptr_t)g,
      (__attribute__((address_space(3))) unsigned int*)(unsigned)(uintptr_t)lds,
      16, 0, 0);
}

// ---------------- merged transpose+convert (w1 & w2, fp16 only) -------------
__global__ void transpose_conv2(const float* __restrict__ w1, const float* __restrict__ w2,
                                _Float16* __restrict__ o1, _Float16* __restrict__ o2) {
  __shared__ float t[32][33];
  int z = blockIdx.z;
  const float* in = z ? w2 : w1;
  _Float16* oh = z ? o2 : o1;
  int R = z ? MLPH : HD, C = z ? HD : MLPH;
  int c0 = (z ? blockIdx.y : blockIdx.x) * 32;
  int r0 = (z ? blockIdx.x : blockIdx.y) * 32;
  int tx = threadIdx.x & 31, ty = threadIdx.x >> 5;
#pragma unroll
  for (int i = 0; i < 4; ++i)
    t[ty + i * 8][tx] = in[(size_t)(r0 + ty + i * 8) * C + c0 + tx];
  __syncthreads();
#pragma unroll
  for (int i = 0; i < 4; ++i)
    oh[(size_t)(c0 + ty + i * 8) * R + r0 + tx] = (_Float16)t[tx][ty + i * 8];
}

// ---------------- merged expert-weight transpose ----------------
__global__ void transpose_f16_2(const float* __restrict__ ew1, const float* __restrict__ ew2,
                                _Float16* __restrict__ ew1t, _Float16* __restrict__ ew2t) {
  __shared__ float t[32][33];
  int z = blockIdx.z;
  const float* in;
  _Float16* out;
  int R, C, c0, r0;
  if (z < 8) {
    in = ew1 + (size_t)z * HD * EXPH; out = ew1t + (size_t)z * HD * EXPH;
    R = HD; C = EXPH; c0 = blockIdx.x * 32; r0 = blockIdx.y * 32;
  } else {
    int e = z - 8;
    in = ew2 + (size_t)e * EXPH * HD; out = ew2t + (size_t)e * EXPH * HD;
    R = EXPH; C = HD; c0 = blockIdx.y * 32; r0 = blockIdx.x * 32;
  }
  int tx = threadIdx.x & 31, ty = threadIdx.x >> 5;
#pragma unroll
  for (int i = 0; i < 4; ++i)
    t[ty + i * 8][tx] = in[(size_t)(r0 + ty + i * 8) * C + c0 + tx];
  __syncthreads();
#pragma unroll
  for (int i = 0; i < 4; ++i)
    out[(size_t)(c0 + ty + i * 8) * R + r0 + tx] = (_Float16)t[tx][ty + i * 8];
}

// ---------------- LN1 (fp16 out) ----------------
__global__ void ln1_kernel(const float* __restrict__ x, const float* __restrict__ g,
                           const float* __restrict__ b, _Float16* __restrict__ oh) {
  int row = blockIdx.x, tid = threadIdx.x;
  const float4* xr = (const float4*)(x + (size_t)row * HD);
  float4 v = xr[tid];
  float s = v.x + v.y + v.z + v.w;
  float s2 = v.x * v.x + v.y * v.y + v.z * v.z + v.w * v.w;
  __shared__ float red[8];
#pragma unroll
  for (int o = 32; o > 0; o >>= 1) { s += __shfl_xor(s, o, 64); s2 += __shfl_xor(s2, o, 64); }
  if ((tid & 63) == 0) { red[tid >> 6] = s; red[(tid >> 6) + 4] = s2; }
  __syncthreads();
  s = red[0] + red[1] + red[2] + red[3];
  s2 = red[4] + red[5] + red[6] + red[7];
  float mu = s * (1.0f / HD);
  float rstd = 1.0f / sqrtf(s2 * (1.0f / HD) - mu * mu + 1e-5f);
  float4 gv = ((const float4*)g)[tid], bv = ((const float4*)b)[tid];
  size_t base = (size_t)row * HD + tid * 4;
  oh[base + 0] = (_Float16)((v.x - mu) * rstd * gv.x + bv.x);
  oh[base + 1] = (_Float16)((v.y - mu) * rstd * gv.y + bv.y);
  oh[base + 2] = (_Float16)((v.z - mu) * rstd * gv.z + bv.z);
  oh[base + 3] = (_Float16)((v.w - mu) * rstd * gv.w + bv.w);
}

// ------- plain fp16 GEMM, gelu epilogue (resmlp gemm1), BK=64, T2 swz -------
__global__ __launch_bounds__(256, 2) void gemm_f16_gelu(
    const _Float16* __restrict__ A, const _Float16* __restrict__ B,
    const float* __restrict__ bias, _Float16* __restrict__ out, int N, int K) {
  int m0 = blockIdx.y * 128, n0 = blockIdx.x * 128;
  __shared__ __align__(16) _Float16 sA[128 * 64], sB[128 * 64];
  int tid = threadIdx.x, wave = tid >> 6, lane = tid & 63;
  int wm = wave >> 1, wn = wave & 1;
  int r16 = lane & 15, q = lane >> 4;
  f32x4v acc[4][4] = {};
  const _Float16* pA = A + (size_t)m0 * K;
  const _Float16* pB = B + (size_t)n0 * K;
  for (int k0 = 0; k0 < K; k0 += 64) {
    __syncthreads();
#pragma unroll
    for (int i = 0; i < 4; ++i) {
      int s = i * 256 + wave * 64 + lane;
      int row = s >> 3, c2 = s & 7;
      int c2s = c2 ^ (row & 7);
      size_t goff = (size_t)row * K + k0 + c2s * 8;
      int loff = (i * 256 + wave * 64) * 16;
      load16_lds(pA + goff, (char*)sA + loff);
      load16_lds(pB + goff, (char*)sB + loff);
    }
    __syncthreads();
#pragma unroll
    for (int ks = 0; ks < 2; ++ks) {
      f16x8 bf[4];
#pragma unroll
      for (int t = 0; t < 4; ++t) {
        int rowb = wn * 64 + t * 16 + r16;
        bf[t] = *(const f16x8*)&sB[rowb * 64 + ((ks * 4 + q) ^ (rowb & 7)) * 8];
      }
#pragma unroll
      for (int mt = 0; mt < 4; ++mt) {
        int rowa = wm * 64 + mt * 16 + r16;
        f16x8 af = *(const f16x8*)&sA[rowa * 64 + ((ks * 4 + q) ^ (rowa & 7)) * 8];
#pragma unroll
        for (int nt = 0; nt < 4; ++nt)
          acc[mt][nt] = __builtin_amdgcn_mfma_f32_16x16x32_f16(af, bf[nt], acc[mt][nt], 0, 0, 0);
      }
    }
  }
#pragma unroll
  for (int mt = 0; mt < 4; ++mt)
#pragma unroll
    for (int nt = 0; nt < 4; ++nt) {
      int col = n0 + wn * 64 + nt * 16 + r16;
      float bv = bias[col];
#pragma unroll
      for (int r = 0; r < 4; ++r) {
        size_t grow = (size_t)(m0 + wm * 64 + mt * 16 + q * 4 + r);
        out[grow * N + col] = (_Float16)gelu_f(acc[mt][nt][r] + bv);
      }
    }
}

// ------- plain fp16 GEMM, split-K partials (resmlp gemm2), BK=64, swz -------
__global__ __launch_bounds__(256, 2) void gemm_f16_pk(
    const _Float16* __restrict__ A, const _Float16* __restrict__ B,
    float* __restrict__ part, int N, int K) {
  // bijective XCD-chunked swizzle over 8*32*KSPLIT = 512 blocks (64/XCD)
  int orig = blockIdx.x + 8 * (blockIdx.y + 32 * blockIdx.z);
  int xcd = orig & 7, idx = orig >> 3;
  int wg = xcd * 64 + idx;
  int bz = wg >> 8;
  int rr = wg & 255;
  int by = rr >> 3, bx = rr & 7;
  int m0 = by * 128, n0 = bx * 128;
  int kbase = bz * KCH;
  __shared__ __align__(16) _Float16 sA[128 * 64], sB[128 * 64];
  int tid = threadIdx.x, wave = tid >> 6, lane = tid & 63;
  int wm = wave >> 1, wn = wave & 1;
  int r16 = lane & 15, q = lane >> 4;
  f32x4v acc[4][4] = {};
  const _Float16* pA = A + (size_t)m0 * K + kbase;
  const _Float16* pB = B + (size_t)n0 * K + kbase;
  for (int k0 = 0; k0 < KCH; k0 += 64) {
    __syncthreads();
#pragma unroll
    for (int i = 0; i < 4; ++i) {
      int s = i * 256 + wave * 64 + lane;
      int row = s >> 3, c2 = s & 7;
      int c2s = c2 ^ (row & 7);
      size_t goff = (size_t)row * K + k0 + c2s * 8;
      int loff = (i * 256 + wave * 64) * 16;
      load16_lds(pA + goff, (char*)sA + loff);
      load16_lds(pB + goff, (char*)sB + loff);
    }
    __syncthreads();
#pragma unroll
    for (int ks = 0; ks < 2; ++ks) {
      f16x8 bf[4];
#pragma unroll
      for (int t = 0; t < 4; ++t) {
        int rowb = wn * 64 + t * 16 + r16;
        bf[t] = *(const f16x8*)&sB[rowb * 64 + ((ks * 4 + q) ^ (rowb & 7)) * 8];
      }
#pragma unroll
      for (int mt = 0; mt < 4; ++mt) {
        int rowa = wm * 64 + mt * 16 + r16;
        f16x8 af = *(const f16x8*)&sA[rowa * 64 + ((ks * 4 + q) ^ (rowa & 7)) * 8];
#pragma unroll
        for (int nt = 0; nt < 4; ++nt)
          acc[mt][nt] = __builtin_amdgcn_mfma_f32_16x16x32_f16(af, bf[nt], acc[mt][nt], 0, 0, 0);
      }
    }
  }
  float* pz = part + (size_t)bz * NTOK * HD;
#pragma unroll
  for (int mt = 0; mt < 4; ++mt)
#pragma unroll
    for (int nt = 0; nt < 4; ++nt) {
      int col = n0 + wn * 64 + nt * 16 + r16;
#pragma unroll
      for (int r = 0; r < 4; ++r) {
        size_t grow = (size_t)(m0 + wm * 64 + mt * 16 + q * 4 + r);
        pz[grow * N + col] = acc[mt][nt][r];
      }
    }
}

// ------- reduce partials + bias + residual + LN2 + router (NO atomics) ------
__global__ void reduce_ln2_router_kernel(
    const float* __restrict__ part, const float* __restrict__ x,
    const float* __restrict__ b2, const float* __restrict__ g,
    const float* __restrict__ b, const float* __restrict__ rw,
    _Float16* __restrict__ x2h, int* __restrict__ tidx, float* __restrict__ twt) {
  int row = blockIdx.x, tid = threadIdx.x;
  int lane = tid & 63, wid = tid >> 6;
  float4 v = {0, 0, 0, 0};
#pragma unroll
  for (int z = 0; z < KSPLIT; ++z) {
    float4 p = ((const float4*)(part + ((size_t)z * NTOK + row) * HD))[tid];
    v.x += p.x; v.y += p.y; v.z += p.z; v.w += p.w;
  }
  float4 bb = ((const float4*)b2)[tid];
  float4 xv = ((const float4*)(x + (size_t)row * HD))[tid];
  v.x += bb.x + xv.x; v.y += bb.y + xv.y; v.z += bb.z + xv.z; v.w += bb.w + xv.w;
  float s = v.x + v.y + v.z + v.w;
  float s2 = v.x * v.x + v.y * v.y + v.z * v.z + v.w * v.w;
  __shared__ float red[8];
  __shared__ float sred[4][8];
#pragma unroll
  for (int o = 32; o > 0; o >>= 1) { s += __shfl_xor(s, o, 64); s2 += __shfl_xor(s2, o, 64); }
  if (lane == 0) { red[wid] = s; red[wid + 4] = s2; }
  __syncthreads();
  s = red[0] + red[1] + red[2] + red[3];
  s2 = red[4] + red[5] + red[6] + red[7];
  float mu = s * (1.0f / HD);
  float rstd = 1.0f / sqrtf(s2 * (1.0f / HD) - mu * mu + 1e-5f);
  float4 gv = ((const float4*)g)[tid], bv = ((const float4*)b)[tid];
  float4 o4;
  o4.x = (v.x - mu) * rstd * gv.x + bv.x + v.x;
  o4.y = (v.y - mu) * rstd * gv.y + bv.y + v.y;
  o4.z = (v.z - mu) * rstd * gv.z + bv.z + v.z;
  o4.w = (v.w - mu) * rstd * gv.w + bv.w + v.w;
  size_t base = (size_t)row * HD + tid * 4;
  x2h[base + 0] = (_Float16)o4.x;
  x2h[base + 1] = (_Float16)o4.y;
  x2h[base + 2] = (_Float16)o4.z;
  x2h[base + 3] = (_Float16)o4.w;
  float lg[8] = {0, 0, 0, 0, 0, 0, 0, 0};
  {
    const float4* rp = (const float4*)(rw + (size_t)tid * 32);
    float xc[4] = {o4.x, o4.y, o4.z, o4.w};
#pragma unroll
    for (int jj = 0; jj < 4; ++jj) {
      float4 r0 = rp[jj * 2], r1 = rp[jj * 2 + 1];
      lg[0] += xc[jj] * r0.x; lg[1] += xc[jj] * r0.y;
      lg[2] += xc[jj] * r0.z; lg[3] += xc[jj] * r0.w;
      lg[4] += xc[jj] * r1.x; lg[5] += xc[jj] * r1.y;
      lg[6] += xc[jj] * r1.z; lg[7] += xc[jj] * r1.w;
    }
  }
#pragma unroll
  for (int o = 32; o > 0; o >>= 1)
#pragma unroll
    for (int e = 0; e < 8; ++e) lg[e] += __shfl_xor(lg[e], o, 64);
  if (lane == 0)
#pragma unroll
    for (int e = 0; e < 8; ++e) sred[wid][e] = lg[e];
  __syncthreads();
  if (tid == 0) {
    float l8[8];
#pragma unroll
    for (int e = 0; e < 8; ++e)
      l8[e] = sred[0][e] + sred[1][e] + sred[2][e] + sred[3][e];
    int e0 = 0; float m0v = l8[0];
#pragma unroll
    for (int e = 1; e < 8; ++e) if (l8[e] > m0v) { m0v = l8[e]; e0 = e; }
    int e1 = -1; float m1v = -3.4e38f;
#pragma unroll
    for (int e = 0; e < 8; ++e) if (e != e0 && l8[e] > m1v) { m1v = l8[e]; e1 = e; }
    float p0 = 1.0f / (1.0f + expf(m1v - m0v));
    tidx[2 * row] = e0; tidx[2 * row + 1] = e1;
    twt[2 * row] = p0; twt[2 * row + 1] = 1.0f - p0;
  }
}

// ------- histogram + offsets + aux + scatter + slot->token (single block) ---
// Ballot-aggregated: one LDS atomic per wave per expert, not per token.
__global__ void route_block(const int* __restrict__ tidx,
                            int* __restrict__ poff_g, float* __restrict__ auxp,
                            int* __restrict__ slotmap, int* __restrict__ slot2token) {
  __shared__ int cnt8[8];
  __shared__ int poff[9];
  __shared__ int cur[8];
  int tid = threadIdx.x, lane = tid & 63;
  if (tid < 8) { cnt8[tid] = 0; cur[tid] = 0; }
  __syncthreads();
  // pass 1: histogram (wave-aggregated)
  for (int t = tid; t < NTOK; t += 256) {
#pragma unroll
    for (int k = 0; k < 2; ++k) {
      int e = tidx[2 * t + k];
#pragma unroll
      for (int ee = 0; ee < NEXP; ++ee) {
        unsigned long long mask = __ballot(e == ee);
        if (e == ee && lane == __ffsll((long long)mask) - 1)
          atomicAdd(&cnt8[ee], (int)__popcll(mask));
      }
    }
  }
  __syncthreads();
  if (tid == 0) {
    int acc = 0; poff[0] = 0; float aux = 0.0f;
    for (int e = 0; e < NEXP; ++e) {
      int c = cnt8[e];
      float load = (float)c / (float)(NTOK * 2);
      aux += load * logf(load + 1e-9f);
      acc += ((c + 127) >> 7) << 7;
      poff[e + 1] = acc;
    }
    auxp[0] = 0.01f * aux;
  }
  __syncthreads();
  // pass 2: scatter (wave-aggregated slot assignment; intra-expert order free)
  for (int t = tid; t < NTOK; t += 256) {
#pragma unroll
    for (int k = 0; k < 2; ++k) {
      int e = tidx[2 * t + k];
      int slot = 0;
#pragma unroll
      for (int ee = 0; ee < NEXP; ++ee) {
        unsigned long long mask = __ballot(e == ee);
        if (e == ee) {
          int leader = __ffsll((long long)mask) - 1;
          int base;
          if (lane == leader) base = atomicAdd(&cur[ee], (int)__popcll(mask));
          base = __shfl(base, leader, 64);
          int rank = (int)__popcll(mask & ((1ULL << lane) - 1ULL));
          slot = poff[ee] + base + rank;
        }
      }
      slotmap[2 * t + k] = slot;
      slot2token[slot] = t;
    }
  }
  __syncthreads();
  // pad slots -> token 0 (compute discarded in combine)
  for (int e = 0; e < NEXP; ++e) {
    int lo = poff[e] + cnt8[e], hi = poff[e + 1];
    for (int s2 = lo + tid; s2 < hi; s2 += 256) slot2token[s2] = 0;
  }
  if (tid < 9) poff_g[tid] = poff[tid];
}

// ------- single-fp16 GEMM (experts, padded buckets), BK=64, swizzled -------
// EPI==0: A rows indirect via slot2token (x2h source), gelu -> fp16
// EPI==1: A rows direct (a1), +bias -> fp32
template <int EPI>
__global__ __launch_bounds__(256, 2) void gemm_expert(
    const _Float16* __restrict__ A, const _Float16* __restrict__ B,
    const float* __restrict__ bias, void* __restrict__ out,
    int N, int K, const int* __restrict__ poff, size_t bstride, int bias_stride,
    const int* __restrict__ s2t) {
  int e = blockIdx.z;
  int lo = poff[e], hi = poff[e + 1];
  int m0 = lo + blockIdx.y * 128;
  if (m0 >= hi) return;
  const _Float16* Bt = B + (size_t)e * bstride;
  const float* bias_e = bias + (size_t)e * bias_stride;
  int n0 = blockIdx.x * 128;
  __shared__ __align__(16) _Float16 sA[128 * 64];
  __shared__ __align__(16) _Float16 sB[128 * 64];
  int tid = threadIdx.x, wave = tid >> 6, lane = tid & 63;
  int wm = wave >> 1, wn = wave & 1;
  int r16 = lane & 15, q = lane >> 4;
  f32x4v acc[4][4] = {};
  size_t aoff[4]; size_t boff[4];
#pragma unroll
  for (int i = 0; i < 4; ++i) {
    int s = i * 256 + wave * 64 + lane;
    int row = s >> 3, c2 = s & 7;
    int c2s = c2 ^ (row & 7);
    int am = m0 + row;
    size_t arow = (EPI == 0) ? (size_t)s2t[am] : (size_t)am;
    aoff[i] = arow * K + c2s * 8;
    boff[i] = (size_t)(n0 + row) * K + c2s * 8;
  }
  for (int k0 = 0; k0 < K; k0 += 64) {
    __syncthreads();
#pragma unroll
    for (int i = 0; i < 4; ++i) {
      int loff = (i * 256 + wave * 64) * 16;
      load16_lds(A + aoff[i] + k0, (char*)sA + loff);
      load16_lds(Bt + boff[i] + k0, (char*)sB + loff);
    }
    __syncthreads();
#pragma unroll
    for (int ks = 0; ks < 2; ++ks) {
      f16x8 bf[4];
#pragma unroll
      for (int t = 0; t < 4; ++t) {
        int rowb = wn * 64 + t * 16 + r16;
        bf[t] = *(const f16x8*)&sB[rowb * 64 + ((ks * 4 + q) ^ (rowb & 7)) * 8];
      }
#pragma unroll
      for (int mt = 0; mt < 4; ++mt) {
        int rowa = wm * 64 + mt * 16 + r16;
        f16x8 af = *(const f16x8*)&sA[rowa * 64 + ((ks * 4 + q) ^ (rowa & 7)) * 8];
#pragma unroll
        for (int nt = 0; nt < 4; ++nt)
          acc[mt][nt] = __builtin_amdgcn_mfma_f32_16x16x32_f16(af, bf[nt], acc[mt][nt], 0, 0, 0);
      }
    }
  }
#pragma unroll
  for (int mt = 0; mt < 4; ++mt)
#pragma unroll
    for (int nt = 0; nt < 4; ++nt) {
      int col = n0 + wn * 64 + nt * 16 + r16;
      float bv = bias_e[col];
#pragma unroll
      for (int r = 0; r < 4; ++r) {
        size_t grow = (size_t)(m0 + wm * 64 + mt * 16 + q * 4 + r);
        float v = acc[mt][nt][r] + bv;
        if (EPI == 0)
          ((_Float16*)out)[grow * N + col] = (_Float16)gelu_f(v);
        else
          ((float*)out)[grow * N + col] = v;
      }
    }
}

// ---------------- combine + final LN ----------------
__global__ void combine_ln_kernel(const float* __restrict__ ybuf, const int* __restrict__ slotmap,
                                  const float* __restrict__ twt, const float* __restrict__ g,
                                  const float* __restrict__ b, float* __restrict__ out) {
  int t = blockIdx.x, tid = threadIdx.x;
  int s0 = slotmap[2 * t], s1 = slotmap[2 * t + 1];
  float w0 = twt[2 * t], w1 = twt[2 * t + 1];
  float4 a = ((const float4*)(ybuf + (size_t)s0 * HD))[tid];
  float4 c = ((const float4*)(ybuf + (size_t)s1 * HD))[tid];
  float4 v;
  v.x = w0 * a.x + w1 * c.x; v.y = w0 * a.y + w1 * c.y;
  v.z = w0 * a.z + w1 * c.z; v.w = w0 * a.w + w1 * c.w;
  float s = v.x + v.y + v.z + v.w;
  float s2 = v.x * v.x + v.y * v.y + v.z * v.z + v.w * v.w;
  __shared__ float red[8];
#pragma unroll
  for (int o = 32; o > 0; o >>= 1) { s += __shfl_xor(s, o, 64); s2 += __shfl_xor(s2, o, 64); }
  if ((tid & 63) == 0) { red[tid >> 6] = s; red[(tid >> 6) + 4] = s2; }
  __syncthreads();
  s = red[0] + red[1] + red[2] + red[3];
  s2 = red[4] + red[5] + red[6] + red[7];
  float mu = s * (1.0f / HD);
  float rstd = 1.0f / sqrtf(s2 * (1.0f / HD) - mu * mu + 1e-5f);
  float4 gv = ((const float4*)g)[tid], bv = ((const float4*)b)[tid];
  float4 o4;
  o4.x = (v.x - mu) * rstd * gv.x + bv.x;
  o4.y = (v.y - mu) * rstd * gv.y + bv.y;
  o4.z = (v.z - mu) * rstd * gv.z + bv.z;
  o4.w = (v.w - mu) * rstd * gv.w + bv.w;
  ((float4*)(out + (size_t)t * HD))[tid] = o4;
}

// ---------------- launch ----------------
extern "C" void kernel_launch(void* const* d_in, const int* in_sizes, int n_in,
                              void* d_out, int out_size, void* d_ws, size_t ws_size,
                              hipStream_t stream) {
  const float* x    = (const float*)d_in[0];
  const float* ln1g = (const float*)d_in[1];
  const float* ln1b = (const float*)d_in[2];
  const float* ln2g = (const float*)d_in[3];
  const float* ln2b = (const float*)d_in[4];
  const float* w1   = (const float*)d_in[5];
  const float* b1   = (const float*)d_in[6];
  const float* w2   = (const float*)d_in[7];
  const float* b2   = (const float*)d_in[8];
  const float* rw   = (const float*)d_in[9];
  const float* ew1  = (const float*)d_in[10];
  const float* eb1  = (const float*)d_in[11];
  const float* ew2  = (const float*)d_in[12];
  const float* eb2  = (const float*)d_in[13];
  const float* lnfg = (const float*)d_in[14];
  const float* lnfb = (const float*)d_in[15];

  char* ws = (char*)d_ws;
  _Float16* acth = (_Float16*)(ws + 0);            // 32 MB [4096,4096] f16
  _Float16* ew2t = (_Float16*)(ws + 0);            // 32 MB (after pk)
  _Float16* ew1t = (_Float16*)(ws + 33554432);     // 32 MB
  _Float16* w1th = (_Float16*)(ws + 67108864);     // 8 MB
  _Float16* x2h  = (_Float16*)(ws + 67108864);     // 8 MB (after gemm1)
  _Float16* w2th = (_Float16*)(ws + 75497472);     // 8 MB
  _Float16* h1h  = (_Float16*)(ws + 100663296);    // 8 MB
  float*    part = (float*)(ws + 100663296);       // KSPLIT x [4096,1024] f32 = 32 MB
  float*    ybuf = (float*)(ws + 100663296);       // [MAXSLOT,1024] f32 (after reduce)
  _Float16* a1   = (_Float16*)(ws + 167772160);    // [MAXSLOT,2048] f16
  const size_t offS = 205520896;
  int*   poff       = (int*)(ws + offS + 64);
  int*   tidx       = (int*)(ws + offS + 1024);
  float* twt        = (float*)(ws + offS + 1024 + 32768);
  int*   slotmap    = (int*)(ws + offS + 1024 + 65536);
  int*   slot2token = (int*)(ws + offS + 1024 + 98304);

  float* out  = (float*)d_out;
  float* auxp = out + (size_t)NTOK * HD;

  dim3 b256(256);

  // resmlp weight conversion (fp16 transposes)
  transpose_conv2<<<dim3(128, 32, 2), b256, 0, stream>>>(w1, w2, w1th, w2th);

  // resmlp
  ln1_kernel<<<NTOK, b256, 0, stream>>>(x, ln1g, ln1b, h1h);
  gemm_f16_gelu<<<dim3(MLPH / 128, NTOK / 128, 1), b256, 0, stream>>>(
      h1h, w1th, b1, acth, MLPH, HD);
  gemm_f16_pk<<<dim3(HD / 128, NTOK / 128, KSPLIT), b256, 0, stream>>>(
      acth, w2th, part, HD, MLPH);
  reduce_ln2_router_kernel<<<NTOK, b256, 0, stream>>>(
      part, x, b2, ln2g, ln2b, rw, x2h, tidx, twt);

  // expert weight transposes (act region now dead)
  transpose_f16_2<<<dim3(64, 32, 16), b256, 0, stream>>>(ew1, ew2, ew1t, ew2t);

  // routing tail (single block): histogram + offsets + aux + scatter
  route_block<<<1, b256, 0, stream>>>(tidx, poff, auxp, slotmap, slot2token);

  // experts (padded buckets, early-exit grid); eg1 gathers A from x2h via s2t
  gemm_expert<0><<<dim3(EXPH / 128, NTOK / 128, NEXP), b256, 0, stream>>>(
      x2h, ew1t, eb1, a1, EXPH, HD, poff, (size_t)EXPH * HD, EXPH, slot2token);
  gemm_expert<1><<<dim3(HD / 128, NTOK / 128, NEXP), b256, 0, stream>>>(
      a1, ew2t, eb2, ybuf, HD, EXPH, poff, (size_t)HD * EXPH, HD, nullptr);

  // combine + final LN
  combine_ln_kernel<<<NTOK, b256, 0, stream>>>(ybuf, slotmap, twt, lnfg, lnfb, out);
}

// Round 4
// 481.119 us; speedup vs baseline: 1.4504x; 1.1311x over previous
//
#include <hip/hip_runtime.h>
#include <cstdint>

// ResMLP + top2-MoE + final LN on MI355X.
// R8: route_block was 76.9 us — ONE block (0.04% occupancy) serializing
// 8192 token-slots through ballot loops + dependent global loads while
// 255 CUs idle. Split into 3 parallel constant-shape kernels:
//   route_hist    (64 blk): per-chunk histogram -> cpart[64][8]
//   route_offsets (1 blk):  reduce + poff + aux + chunk-base prefix + pads
//   route_scatter (64 blk): per-chunk slot assignment from cbase via LDS cur
// Intra-expert slot order is arbitrary -> per-chunk atomic assignment valid.

#define NTOK 4096
#define HD 1024
#define MLPH 4096
#define EXPH 2048
#define NEXP 8
#define KSPLIT 2
#define KCH 2048
#define MAXSLOT 9216
#define NCH 64   // routing chunks; NTOK*2/NCH = 128 entries per chunk

typedef __attribute__((ext_vector_type(8))) _Float16 f16x8;
typedef __attribute__((ext_vector_type(4))) float f32x4v;

__device__ __forceinline__ float gelu_f(float v) {
  return 0.5f * v * (1.0f + erff(v * 0.7071067811865475f));
}

__device__ __forceinline__ void load16_lds(const void* g, void* lds) {
  __builtin_amdgcn_global_load_lds(
      (__attribute__((address_space(1))) unsigned int*)(uintptr_t)g,
      (__attribute__((address_space(3))) unsigned int*)(unsigned)(uintptr_t)lds,
      16, 0, 0);
}

// ---------------- merged transpose+convert (w1 & w2, fp16 only) -------------
__global__ void transpose_conv2(const float* __restrict__ w1, const float* __restrict__ w2,
                                _Float16* __restrict__ o1, _Float16* __restrict__ o2) {
  __shared__ float t[32][33];
  int z = blockIdx.z;
  const float* in = z ? w2 : w1;
  _Float16* oh = z ? o2 : o1;
  int R = z ? MLPH : HD, C = z ? HD : MLPH;
  int c0 = (z ? blockIdx.y : blockIdx.x) * 32;
  int r0 = (z ? blockIdx.x : blockIdx.y) * 32;
  int tx = threadIdx.x & 31, ty = threadIdx.x >> 5;
#pragma unroll
  for (int i = 0; i < 4; ++i)
    t[ty + i * 8][tx] = in[(size_t)(r0 + ty + i * 8) * C + c0 + tx];
  __syncthreads();
#pragma unroll
  for (int i = 0; i < 4; ++i)
    oh[(size_t)(c0 + ty + i * 8) * R + r0 + tx] = (_Float16)t[tx][ty + i * 8];
}

// ---------------- merged expert-weight transpose ----------------
__global__ void transpose_f16_2(const float* __restrict__ ew1, const float* __restrict__ ew2,
                                _Float16* __restrict__ ew1t, _Float16* __restrict__ ew2t) {
  __shared__ float t[32][33];
  int z = blockIdx.z;
  const float* in;
  _Float16* out;
  int R, C, c0, r0;
  if (z < 8) {
    in = ew1 + (size_t)z * HD * EXPH; out = ew1t + (size_t)z * HD * EXPH;
    R = HD; C = EXPH; c0 = blockIdx.x * 32; r0 = blockIdx.y * 32;
  } else {
    int e = z - 8;
    in = ew2 + (size_t)e * EXPH * HD; out = ew2t + (size_t)e * EXPH * HD;
    R = EXPH; C = HD; c0 = blockIdx.y * 32; r0 = blockIdx.x * 32;
  }
  int tx = threadIdx.x & 31, ty = threadIdx.x >> 5;
#pragma unroll
  for (int i = 0; i < 4; ++i)
    t[ty + i * 8][tx] = in[(size_t)(r0 + ty + i * 8) * C + c0 + tx];
  __syncthreads();
#pragma unroll
  for (int i = 0; i < 4; ++i)
    out[(size_t)(c0 + ty + i * 8) * R + r0 + tx] = (_Float16)t[tx][ty + i * 8];
}

// ---------------- LN1 (fp16 out) ----------------
__global__ void ln1_kernel(const float* __restrict__ x, const float* __restrict__ g,
                           const float* __restrict__ b, _Float16* __restrict__ oh) {
  int row = blockIdx.x, tid = threadIdx.x;
  const float4* xr = (const float4*)(x + (size_t)row * HD);
  float4 v = xr[tid];
  float s = v.x + v.y + v.z + v.w;
  float s2 = v.x * v.x + v.y * v.y + v.z * v.z + v.w * v.w;
  __shared__ float red[8];
#pragma unroll
  for (int o = 32; o > 0; o >>= 1) { s += __shfl_xor(s, o, 64); s2 += __shfl_xor(s2, o, 64); }
  if ((tid & 63) == 0) { red[tid >> 6] = s; red[(tid >> 6) + 4] = s2; }
  __syncthreads();
  s = red[0] + red[1] + red[2] + red[3];
  s2 = red[4] + red[5] + red[6] + red[7];
  float mu = s * (1.0f / HD);
  float rstd = 1.0f / sqrtf(s2 * (1.0f / HD) - mu * mu + 1e-5f);
  float4 gv = ((const float4*)g)[tid], bv = ((const float4*)b)[tid];
  size_t base = (size_t)row * HD + tid * 4;
  oh[base + 0] = (_Float16)((v.x - mu) * rstd * gv.x + bv.x);
  oh[base + 1] = (_Float16)((v.y - mu) * rstd * gv.y + bv.y);
  oh[base + 2] = (_Float16)((v.z - mu) * rstd * gv.z + bv.z);
  oh[base + 3] = (_Float16)((v.w - mu) * rstd * gv.w + bv.w);
}

// ------- plain fp16 GEMM, gelu epilogue (resmlp gemm1), BK=64, T2 swz -------
__global__ __launch_bounds__(256, 2) void gemm_f16_gelu(
    const _Float16* __restrict__ A, const _Float16* __restrict__ B,
    const float* __restrict__ bias, _Float16* __restrict__ out, int N, int K) {
  int m0 = blockIdx.y * 128, n0 = blockIdx.x * 128;
  __shared__ __align__(16) _Float16 sA[128 * 64], sB[128 * 64];
  int tid = threadIdx.x, wave = tid >> 6, lane = tid & 63;
  int wm = wave >> 1, wn = wave & 1;
  int r16 = lane & 15, q = lane >> 4;
  f32x4v acc[4][4] = {};
  const _Float16* pA = A + (size_t)m0 * K;
  const _Float16* pB = B + (size_t)n0 * K;
  for (int k0 = 0; k0 < K; k0 += 64) {
    __syncthreads();
#pragma unroll
    for (int i = 0; i < 4; ++i) {
      int s = i * 256 + wave * 64 + lane;
      int row = s >> 3, c2 = s & 7;
      int c2s = c2 ^ (row & 7);
      size_t goff = (size_t)row * K + k0 + c2s * 8;
      int loff = (i * 256 + wave * 64) * 16;
      load16_lds(pA + goff, (char*)sA + loff);
      load16_lds(pB + goff, (char*)sB + loff);
    }
    __syncthreads();
#pragma unroll
    for (int ks = 0; ks < 2; ++ks) {
      f16x8 bf[4];
#pragma unroll
      for (int t = 0; t < 4; ++t) {
        int rowb = wn * 64 + t * 16 + r16;
        bf[t] = *(const f16x8*)&sB[rowb * 64 + ((ks * 4 + q) ^ (rowb & 7)) * 8];
      }
#pragma unroll
      for (int mt = 0; mt < 4; ++mt) {
        int rowa = wm * 64 + mt * 16 + r16;
        f16x8 af = *(const f16x8*)&sA[rowa * 64 + ((ks * 4 + q) ^ (rowa & 7)) * 8];
#pragma unroll
        for (int nt = 0; nt < 4; ++nt)
          acc[mt][nt] = __builtin_amdgcn_mfma_f32_16x16x32_f16(af, bf[nt], acc[mt][nt], 0, 0, 0);
      }
    }
  }
#pragma unroll
  for (int mt = 0; mt < 4; ++mt)
#pragma unroll
    for (int nt = 0; nt < 4; ++nt) {
      int col = n0 + wn * 64 + nt * 16 + r16;
      float bv = bias[col];
#pragma unroll
      for (int r = 0; r < 4; ++r) {
        size_t grow = (size_t)(m0 + wm * 64 + mt * 16 + q * 4 + r);
        out[grow * N + col] = (_Float16)gelu_f(acc[mt][nt][r] + bv);
      }
    }
}

// ------- plain fp16 GEMM, split-K partials (resmlp gemm2), BK=64, swz -------
__global__ __launch_bounds__(256, 2) void gemm_f16_pk(
    const _Float16* __restrict__ A, const _Float16* __restrict__ B,
    float* __restrict__ part, int N, int K) {
  // bijective XCD-chunked swizzle over 8*32*KSPLIT = 512 blocks (64/XCD)
  int orig = blockIdx.x + 8 * (blockIdx.y + 32 * blockIdx.z);
  int xcd = orig & 7, idx = orig >> 3;
  int wg = xcd * 64 + idx;
  int bz = wg >> 8;
  int rr = wg & 255;
  int by = rr >> 3, bx = rr & 7;
  int m0 = by * 128, n0 = bx * 128;
  int kbase = bz * KCH;
  __shared__ __align__(16) _Float16 sA[128 * 64], sB[128 * 64];
  int tid = threadIdx.x, wave = tid >> 6, lane = tid & 63;
  int wm = wave >> 1, wn = wave & 1;
  int r16 = lane & 15, q = lane >> 4;
  f32x4v acc[4][4] = {};
  const _Float16* pA = A + (size_t)m0 * K + kbase;
  const _Float16* pB = B + (size_t)n0 * K + kbase;
  for (int k0 = 0; k0 < KCH; k0 += 64) {
    __syncthreads();
#pragma unroll
    for (int i = 0; i < 4; ++i) {
      int s = i * 256 + wave * 64 + lane;
      int row = s >> 3, c2 = s & 7;
      int c2s = c2 ^ (row & 7);
      size_t goff = (size_t)row * K + k0 + c2s * 8;
      int loff = (i * 256 + wave * 64) * 16;
      load16_lds(pA + goff, (char*)sA + loff);
      load16_lds(pB + goff, (char*)sB + loff);
    }
    __syncthreads();
#pragma unroll
    for (int ks = 0; ks < 2; ++ks) {
      f16x8 bf[4];
#pragma unroll
      for (int t = 0; t < 4; ++t) {
        int rowb = wn * 64 + t * 16 + r16;
        bf[t] = *(const f16x8*)&sB[rowb * 64 + ((ks * 4 + q) ^ (rowb & 7)) * 8];
      }
#pragma unroll
      for (int mt = 0; mt < 4; ++mt) {
        int rowa = wm * 64 + mt * 16 + r16;
        f16x8 af = *(const f16x8*)&sA[rowa * 64 + ((ks * 4 + q) ^ (rowa & 7)) * 8];
#pragma unroll
        for (int nt = 0; nt < 4; ++nt)
          acc[mt][nt] = __builtin_amdgcn_mfma_f32_16x16x32_f16(af, bf[nt], acc[mt][nt], 0, 0, 0);
      }
    }
  }
  float* pz = part + (size_t)bz * NTOK * HD;
#pragma unroll
  for (int mt = 0; mt < 4; ++mt)
#pragma unroll
    for (int nt = 0; nt < 4; ++nt) {
      int col = n0 + wn * 64 + nt * 16 + r16;
#pragma unroll
      for (int r = 0; r < 4; ++r) {
        size_t grow = (size_t)(m0 + wm * 64 + mt * 16 + q * 4 + r);
        pz[grow * N + col] = acc[mt][nt][r];
      }
    }
}

// ------- reduce partials + bias + residual + LN2 + router (NO atomics) ------
__global__ void reduce_ln2_router_kernel(
    const float* __restrict__ part, const float* __restrict__ x,
    const float* __restrict__ b2, const float* __restrict__ g,
    const float* __restrict__ b, const float* __restrict__ rw,
    _Float16* __restrict__ x2h, int* __restrict__ tidx, float* __restrict__ twt) {
  int row = blockIdx.x, tid = threadIdx.x;
  int lane = tid & 63, wid = tid >> 6;
  float4 v = {0, 0, 0, 0};
#pragma unroll
  for (int z = 0; z < KSPLIT; ++z) {
    float4 p = ((const float4*)(part + ((size_t)z * NTOK + row) * HD))[tid];
    v.x += p.x; v.y += p.y; v.z += p.z; v.w += p.w;
  }
  float4 bb = ((const float4*)b2)[tid];
  float4 xv = ((const float4*)(x + (size_t)row * HD))[tid];
  v.x += bb.x + xv.x; v.y += bb.y + xv.y; v.z += bb.z + xv.z; v.w += bb.w + xv.w;
  float s = v.x + v.y + v.z + v.w;
  float s2 = v.x * v.x + v.y * v.y + v.z * v.z + v.w * v.w;
  __shared__ float red[8];
  __shared__ float sred[4][8];
#pragma unroll
  for (int o = 32; o > 0; o >>= 1) { s += __shfl_xor(s, o, 64); s2 += __shfl_xor(s2, o, 64); }
  if (lane == 0) { red[wid] = s; red[wid + 4] = s2; }
  __syncthreads();
  s = red[0] + red[1] + red[2] + red[3];
  s2 = red[4] + red[5] + red[6] + red[7];
  float mu = s * (1.0f / HD);
  float rstd = 1.0f / sqrtf(s2 * (1.0f / HD) - mu * mu + 1e-5f);
  float4 gv = ((const float4*)g)[tid], bv = ((const float4*)b)[tid];
  float4 o4;
  o4.x = (v.x - mu) * rstd * gv.x + bv.x + v.x;
  o4.y = (v.y - mu) * rstd * gv.y + bv.y + v.y;
  o4.z = (v.z - mu) * rstd * gv.z + bv.z + v.z;
  o4.w = (v.w - mu) * rstd * gv.w + bv.w + v.w;
  size_t base = (size_t)row * HD + tid * 4;
  x2h[base + 0] = (_Float16)o4.x;
  x2h[base + 1] = (_Float16)o4.y;
  x2h[base + 2] = (_Float16)o4.z;
  x2h[base + 3] = (_Float16)o4.w;
  float lg[8] = {0, 0, 0, 0, 0, 0, 0, 0};
  {
    const float4* rp = (const float4*)(rw + (size_t)tid * 32);
    float xc[4] = {o4.x, o4.y, o4.z, o4.w};
#pragma unroll
    for (int jj = 0; jj < 4; ++jj) {
      float4 r0 = rp[jj * 2], r1 = rp[jj * 2 + 1];
      lg[0] += xc[jj] * r0.x; lg[1] += xc[jj] * r0.y;
      lg[2] += xc[jj] * r0.z; lg[3] += xc[jj] * r0.w;
      lg[4] += xc[jj] * r1.x; lg[5] += xc[jj] * r1.y;
      lg[6] += xc[jj] * r1.z; lg[7] += xc[jj] * r1.w;
    }
  }
#pragma unroll
  for (int o = 32; o > 0; o >>= 1)
#pragma unroll
    for (int e = 0; e < 8; ++e) lg[e] += __shfl_xor(lg[e], o, 64);
  if (lane == 0)
#pragma unroll
    for (int e = 0; e < 8; ++e) sred[wid][e] = lg[e];
  __syncthreads();
  if (tid == 0) {
    float l8[8];
#pragma unroll
    for (int e = 0; e < 8; ++e)
      l8[e] = sred[0][e] + sred[1][e] + sred[2][e] + sred[3][e];
    int e0 = 0; float m0v = l8[0];
#pragma unroll
    for (int e = 1; e < 8; ++e) if (l8[e] > m0v) { m0v = l8[e]; e0 = e; }
    int e1 = -1; float m1v = -3.4e38f;
#pragma unroll
    for (int e = 0; e < 8; ++e) if (e != e0 && l8[e] > m1v) { m1v = l8[e]; e1 = e; }
    float p0 = 1.0f / (1.0f + expf(m1v - m0v));
    tidx[2 * row] = e0; tidx[2 * row + 1] = e1;
    twt[2 * row] = p0; twt[2 * row + 1] = 1.0f - p0;
  }
}

// ------- routing pass 1: per-chunk histogram (NCH blocks x 128 thr) -------
__global__ void route_hist(const int* __restrict__ tidx, int* __restrict__ cpart) {
  __shared__ int c8[8];
  int b = blockIdx.x, tid = threadIdx.x;
  if (tid < 8) c8[tid] = 0;
  __syncthreads();
  int e = tidx[b * (NTOK * 2 / NCH) + tid];
  atomicAdd(&c8[e], 1);
  __syncthreads();
  if (tid < 8) cpart[b * 8 + tid] = c8[tid];
}

// ------- routing pass 2: offsets + aux + chunk bases + pad fill (1 block) ---
__global__ void route_offsets(const int* __restrict__ cpart,
                              int* __restrict__ poff_g, float* __restrict__ auxp,
                              int* __restrict__ cbase, int* __restrict__ slot2token) {
  __shared__ int sc[NCH * 8];
  __shared__ int cnt8[8];
  __shared__ int poff[9];
  int tid = threadIdx.x;
  sc[tid] = cpart[tid];
  sc[tid + 256] = cpart[tid + 256];
  __syncthreads();
  if (tid < 8) {
    int acc = 0;
    for (int b = 0; b < NCH; ++b) acc += sc[b * 8 + tid];
    cnt8[tid] = acc;
  }
  __syncthreads();
  if (tid == 0) {
    int acc = 0; poff[0] = 0; float aux = 0.0f;
    for (int e = 0; e < NEXP; ++e) {
      int c = cnt8[e];
      float load = (float)c / (float)(NTOK * 2);
      aux += load * logf(load + 1e-9f);
      acc += ((c + 127) >> 7) << 7;
      poff[e + 1] = acc;
    }
    auxp[0] = 0.01f * aux;
  }
  __syncthreads();
  if (tid < 8) {
    int acc = poff[tid];
    for (int b = 0; b < NCH; ++b) {
      cbase[b * 8 + tid] = acc;
      acc += sc[b * 8 + tid];
    }
  }
  // pad slots -> token 0 (compute discarded in combine)
  for (int e = 0; e < NEXP; ++e) {
    int lo = poff[e] + cnt8[e], hi = poff[e + 1];
    for (int s2 = lo + tid; s2 < hi; s2 += 256) slot2token[s2] = 0;
  }
  if (tid < 9) poff_g[tid] = poff[tid];
}

// ------- routing pass 3: per-chunk scatter (NCH blocks x 128 thr) -------
__global__ void route_scatter(const int* __restrict__ tidx, const int* __restrict__ cbase,
                              int* __restrict__ slotmap, int* __restrict__ slot2token) {
  __shared__ int cur[8];
  int b = blockIdx.x, tid = threadIdx.x;
  if (tid < 8) cur[tid] = cbase[b * 8 + tid];
  __syncthreads();
  int i = b * (NTOK * 2 / NCH) + tid;
  int e = tidx[i];
  int slot = atomicAdd(&cur[e], 1);
  slotmap[i] = slot;
  slot2token[slot] = i >> 1;
}

// ------- single-fp16 GEMM (experts, padded buckets), BK=64, swizzled -------
// EPI==0: A rows indirect via slot2token (x2h source), gelu -> fp16
// EPI==1: A rows direct (a1), +bias -> fp32
template <int EPI>
__global__ __launch_bounds__(256, 2) void gemm_expert(
    const _Float16* __restrict__ A, const _Float16* __restrict__ B,
    const float* __restrict__ bias, void* __restrict__ out,
    int N, int K, const int* __restrict__ poff, size_t bstride, int bias_stride,
    const int* __restrict__ s2t) {
  int e = blockIdx.z;
  int lo = poff[e], hi = poff[e + 1];
  int m0 = lo + blockIdx.y * 128;
  if (m0 >= hi) return;
  const _Float16* Bt = B + (size_t)e * bstride;
  const float* bias_e = bias + (size_t)e * bias_stride;
  int n0 = blockIdx.x * 128;
  __shared__ __align__(16) _Float16 sA[128 * 64];
  __shared__ __align__(16) _Float16 sB[128 * 64];
  int tid = threadIdx.x, wave = tid >> 6, lane = tid & 63;
  int wm = wave >> 1, wn = wave & 1;
  int r16 = lane & 15, q = lane >> 4;
  f32x4v acc[4][4] = {};
  size_t aoff[4]; size_t boff[4];
#pragma unroll
  for (int i = 0; i < 4; ++i) {
    int s = i * 256 + wave * 64 + lane;
    int row = s >> 3, c2 = s & 7;
    int c2s = c2 ^ (row & 7);
    int am = m0 + row;
    size_t arow = (EPI == 0) ? (size_t)s2t[am] : (size_t)am;
    aoff[i] = arow * K + c2s * 8;
    boff[i] = (size_t)(n0 + row) * K + c2s * 8;
  }
  for (int k0 = 0; k0 < K; k0 += 64) {
    __syncthreads();
#pragma unroll
    for (int i = 0; i < 4; ++i) {
      int loff = (i * 256 + wave * 64) * 16;
      load16_lds(A + aoff[i] + k0, (char*)sA + loff);
      load16_lds(Bt + boff[i] + k0, (char*)sB + loff);
    }
    __syncthreads();
#pragma unroll
    for (int ks = 0; ks < 2; ++ks) {
      f16x8 bf[4];
#pragma unroll
      for (int t = 0; t < 4; ++t) {
        int rowb = wn * 64 + t * 16 + r16;
        bf[t] = *(const f16x8*)&sB[rowb * 64 + ((ks * 4 + q) ^ (rowb & 7)) * 8];
      }
#pragma unroll
      for (int mt = 0; mt < 4; ++mt) {
        int rowa = wm * 64 + mt * 16 + r16;
        f16x8 af = *(const f16x8*)&sA[rowa * 64 + ((ks * 4 + q) ^ (rowa & 7)) * 8];
#pragma unroll
        for (int nt = 0; nt < 4; ++nt)
          acc[mt][nt] = __builtin_amdgcn_mfma_f32_16x16x32_f16(af, bf[nt], acc[mt][nt], 0, 0, 0);
      }
    }
  }
#pragma unroll
  for (int mt = 0; mt < 4; ++mt)
#pragma unroll
    for (int nt = 0; nt < 4; ++nt) {
      int col = n0 + wn * 64 + nt * 16 + r16;
      float bv = bias_e[col];
#pragma unroll
      for (int r = 0; r < 4; ++r) {
        size_t grow = (size_t)(m0 + wm * 64 + mt * 16 + q * 4 + r);
        float v = acc[mt][nt][r] + bv;
        if (EPI == 0)
          ((_Float16*)out)[grow * N + col] = (_Float16)gelu_f(v);
        else
          ((float*)out)[grow * N + col] = v;
      }
    }
}

// ---------------- combine + final LN ----------------
__global__ void combine_ln_kernel(const float* __restrict__ ybuf, const int* __restrict__ slotmap,
                                  const float* __restrict__ twt, const float* __restrict__ g,
                                  const float* __restrict__ b, float* __restrict__ out) {
  int t = blockIdx.x, tid = threadIdx.x;
  int s0 = slotmap[2 * t], s1 = slotmap[2 * t + 1];
  float w0 = twt[2 * t], w1 = twt[2 * t + 1];
  float4 a = ((const float4*)(ybuf + (size_t)s0 * HD))[tid];
  float4 c = ((const float4*)(ybuf + (size_t)s1 * HD))[tid];
  float4 v;
  v.x = w0 * a.x + w1 * c.x; v.y = w0 * a.y + w1 * c.y;
  v.z = w0 * a.z + w1 * c.z; v.w = w0 * a.w + w1 * c.w;
  float s = v.x + v.y + v.z + v.w;
  float s2 = v.x * v.x + v.y * v.y + v.z * v.z + v.w * v.w;
  __shared__ float red[8];
#pragma unroll
  for (int o = 32; o > 0; o >>= 1) { s += __shfl_xor(s, o, 64); s2 += __shfl_xor(s2, o, 64); }
  if ((tid & 63) == 0) { red[tid >> 6] = s; red[(tid >> 6) + 4] = s2; }
  __syncthreads();
  s = red[0] + red[1] + red[2] + red[3];
  s2 = red[4] + red[5] + red[6] + red[7];
  float mu = s * (1.0f / HD);
  float rstd = 1.0f / sqrtf(s2 * (1.0f / HD) - mu * mu + 1e-5f);
  float4 gv = ((const float4*)g)[tid], bv = ((const float4*)b)[tid];
  float4 o4;
  o4.x = (v.x - mu) * rstd * gv.x + bv.x;
  o4.y = (v.y - mu) * rstd * gv.y + bv.y;
  o4.z = (v.z - mu) * rstd * gv.z + bv.z;
  o4.w = (v.w - mu) * rstd * gv.w + bv.w;
  ((float4*)(out + (size_t)t * HD))[tid] = o4;
}

// ---------------- launch ----------------
extern "C" void kernel_launch(void* const* d_in, const int* in_sizes, int n_in,
                              void* d_out, int out_size, void* d_ws, size_t ws_size,
                              hipStream_t stream) {
  const float* x    = (const float*)d_in[0];
  const float* ln1g = (const float*)d_in[1];
  const float* ln1b = (const float*)d_in[2];
  const float* ln2g = (const float*)d_in[3];
  const float* ln2b = (const float*)d_in[4];
  const float* w1   = (const float*)d_in[5];
  const float* b1   = (const float*)d_in[6];
  const float* w2   = (const float*)d_in[7];
  const float* b2   = (const float*)d_in[8];
  const float* rw   = (const float*)d_in[9];
  const float* ew1  = (const float*)d_in[10];
  const float* eb1  = (const float*)d_in[11];
  const float* ew2  = (const float*)d_in[12];
  const float* eb2  = (const float*)d_in[13];
  const float* lnfg = (const float*)d_in[14];
  const float* lnfb = (const float*)d_in[15];

  char* ws = (char*)d_ws;
  _Float16* acth = (_Float16*)(ws + 0);            // 32 MB [4096,4096] f16
  _Float16* ew2t = (_Float16*)(ws + 0);            // 32 MB (after pk)
  _Float16* ew1t = (_Float16*)(ws + 33554432);     // 32 MB
  _Float16* w1th = (_Float16*)(ws + 67108864);     // 8 MB
  _Float16* x2h  = (_Float16*)(ws + 67108864);     // 8 MB (after gemm1)
  _Float16* w2th = (_Float16*)(ws + 75497472);     // 8 MB
  _Float16* h1h  = (_Float16*)(ws + 100663296);    // 8 MB
  float*    part = (float*)(ws + 100663296);       // KSPLIT x [4096,1024] f32 = 32 MB
  float*    ybuf = (float*)(ws + 100663296);       // [MAXSLOT,1024] f32 (after reduce)
  _Float16* a1   = (_Float16*)(ws + 167772160);    // [MAXSLOT,2048] f16
  const size_t offS = 205520896;
  int*   poff       = (int*)(ws + offS + 64);
  int*   tidx       = (int*)(ws + offS + 1024);
  float* twt        = (float*)(ws + offS + 1024 + 32768);
  int*   slotmap    = (int*)(ws + offS + 1024 + 65536);
  int*   slot2token = (int*)(ws + offS + 1024 + 98304);            // MAXSLOT*4 = 36864
  int*   cpart      = (int*)(ws + offS + 1024 + 98304 + 36864);    // NCH*8*4 = 2048
  int*   cbase      = (int*)(ws + offS + 1024 + 98304 + 36864 + 2048);

  float* out  = (float*)d_out;
  float* auxp = out + (size_t)NTOK * HD;

  dim3 b256(256);

  // resmlp weight conversion (fp16 transposes)
  transpose_conv2<<<dim3(128, 32, 2), b256, 0, stream>>>(w1, w2, w1th, w2th);

  // resmlp
  ln1_kernel<<<NTOK, b256, 0, stream>>>(x, ln1g, ln1b, h1h);
  gemm_f16_gelu<<<dim3(MLPH / 128, NTOK / 128, 1), b256, 0, stream>>>(
      h1h, w1th, b1, acth, MLPH, HD);
  gemm_f16_pk<<<dim3(HD / 128, NTOK / 128, KSPLIT), b256, 0, stream>>>(
      acth, w2th, part, HD, MLPH);
  reduce_ln2_router_kernel<<<NTOK, b256, 0, stream>>>(
      part, x, b2, ln2g, ln2b, rw, x2h, tidx, twt);

  // routing (parallel, constant-shape)
  route_hist<<<NCH, dim3(128), 0, stream>>>(tidx, cpart);
  route_offsets<<<1, b256, 0, stream>>>(cpart, poff, auxp, cbase, slot2token);
  route_scatter<<<NCH, dim3(128), 0, stream>>>(tidx, cbase, slotmap, slot2token);

  // expert weight transposes (act region now dead)
  transpose_f16_2<<<dim3(64, 32, 16), b256, 0, stream>>>(ew1, ew2, ew1t, ew2t);

  // experts (padded buckets, early-exit grid); eg1 gathers A from x2h via s2t
  gemm_expert<0><<<dim3(EXPH / 128, NTOK / 128, NEXP), b256, 0, stream>>>(
      x2h, ew1t, eb1, a1, EXPH, HD, poff, (size_t)EXPH * HD, EXPH, slot2token);
  gemm_expert<1><<<dim3(HD / 128, NTOK / 128, NEXP), b256, 0, stream>>>(
      a1, ew2t, eb2, ybuf, HD, EXPH, poff, (size_t)HD * EXPH, HD, nullptr);

  // combine + final LN
  combine_ln_kernel<<<NTOK, b256, 0, stream>>>(ybuf, slotmap, twt, lnfg, lnfb, out);
}